// Round 3
// baseline (5716.105 us; speedup 1.0000x reference)
//
#include <hip/hip_runtime.h>
#include <hip/hip_bf16.h>

// GraphConv: out = relu( scatter_add_{edges}( edge_val * (feat @ W)[edge_col] -> edge_row ) )
// Dtypes (R1 NaN => fp32 inputs; contract: output = reference dtype = fp32):
//   feat/W/edge_val = float32, edge_row/col = int32, OUTPUT = float32.
// Stage 1: zero d_out (fp32 accumulator IS d_out — no big ws accum, defuses ws_size risk)
// Stage 2: MFMA bf16 GEMM (fp32 in) -> support bf16 in d_ws (25.6 MB only)
// Stage 3: per-edge gather (16 lanes/edge, 16B) + fp32 global_atomic_add into d_out
// Stage 4: in-place fp32 ReLU on d_out

#define N_NODES 100000
#define N_EDGES 1600000
#define D 128

typedef __attribute__((ext_vector_type(8))) short short8;
typedef __attribute__((ext_vector_type(4))) float floatx4;

union U16B { uint4 u4; short8 s8; uint u[4]; ushort us[8]; };

__device__ __forceinline__ ushort f32_to_bf16(float f) {
    uint b = __float_as_uint(f);
    return (ushort)((b + 0x7FFFu + ((b >> 16) & 1u)) >> 16);   // RNE; inputs finite
}
__device__ __forceinline__ float bf16_to_f32(ushort u) {
    return __uint_as_float((uint)u << 16);
}

// ---------------- Stage 1: zero d_out (fp32) ----------------------------------------------
__global__ __launch_bounds__(256) void zero_kernel(float4* __restrict__ acc, int n4) {
    int i = blockIdx.x * 256 + threadIdx.x;
    if (i < n4) acc[i] = make_float4(0.f, 0.f, 0.f, 0.f);
}

// ---------------- Stage 2: support = bf16( fp32 feat @ fp32 W ) via MFMA ------------------
// 4 waves/block, wave owns 16 rows x 128 cols. A-frag: row m=lane&15, quad g=lane>>4 holds k=g*8+j.
// W repacked to fragment-linear bf16 LDS: (k,n) -> Bp[((k>>3)*128+n)*8 + (k&7)].
__global__ __launch_bounds__(256) void gemm_kernel(const float* __restrict__ feat,
                                                   const float* __restrict__ W,
                                                   ushort* __restrict__ support) {
    __shared__ ushort Bp[D * D];   // 32 KB
    const int tid = threadIdx.x;
    for (int e = tid; e < D * D; e += 256) {
        int k = e >> 7, n = e & 127;
        Bp[(((k >> 3) * D + n) << 3) | (k & 7)] = f32_to_bf16(W[e]);
    }
    __syncthreads();

    const int wave = tid >> 6, lane = tid & 63;
    const int row0 = blockIdx.x * 64 + wave * 16;
    if (row0 >= N_NODES) return;              // wave-uniform, after barrier

    const int m = lane & 15, g = lane >> 4;
    floatx4 acc[8];
    const floatx4 z = {0.f, 0.f, 0.f, 0.f};
    #pragma unroll
    for (int t = 0; t < 8; t++) acc[t] = z;

    const float* arow = feat + (size_t)(row0 + m) * D;
    #pragma unroll
    for (int s = 0; s < 4; s++) {             // k-steps of 32
        float4 a0 = *(const float4*)(arow + s * 32 + g * 8);
        float4 a1 = *(const float4*)(arow + s * 32 + g * 8 + 4);
        U16B a;
        a.us[0] = f32_to_bf16(a0.x); a.us[1] = f32_to_bf16(a0.y);
        a.us[2] = f32_to_bf16(a0.z); a.us[3] = f32_to_bf16(a0.w);
        a.us[4] = f32_to_bf16(a1.x); a.us[5] = f32_to_bf16(a1.y);
        a.us[6] = f32_to_bf16(a1.z); a.us[7] = f32_to_bf16(a1.w);
        #pragma unroll
        for (int t = 0; t < 8; t++) {         // 8 col-tiles of 16
            const int chunk = (s * 4 + g) * D + t * 16 + m;
            U16B b; b.u4 = *(const uint4*)(Bp + chunk * 8);
            acc[t] = __builtin_amdgcn_mfma_f32_16x16x32_bf16(a.s8, b.s8, acc[t], 0, 0, 0);
        }
    }
    // C/D: col = lane&15, row = (lane>>4)*4 + reg  (m89-verified)
    #pragma unroll
    for (int t = 0; t < 8; t++) {
        #pragma unroll
        for (int r = 0; r < 4; r++) {
            const int row = row0 + g * 4 + r;
            const int col = t * 16 + m;
            support[(size_t)row * D + col] = f32_to_bf16(acc[t][r]);
        }
    }
}

// ---------------- Stage 3: gather bf16 support, fp32 atomic scatter into d_out ------------
// 16 lanes per edge; lane gathers 16B (8 bf16), scales in fp32, 8x global_atomic_add_f32.
__global__ __launch_bounds__(256) void spmm_kernel(const ushort* __restrict__ support,
                                                   const float* __restrict__ edge_val,
                                                   const int* __restrict__ edge_row,
                                                   const int* __restrict__ edge_col,
                                                   float* __restrict__ out) {
    const long gtid = (long)blockIdx.x * 256 + threadIdx.x;
    const int edge = (int)(gtid >> 4);
    const int part = (int)(gtid & 15);
    if (edge >= N_EDGES) return;

    const int col = edge_col[edge];
    const int row = edge_row[edge];
    const float v = edge_val[edge];

    U16B s;
    s.u4 = *(const uint4*)(support + (size_t)col * D + part * 8);

    float* dst = out + (size_t)row * D + part * 8;
    #pragma unroll
    for (int i = 0; i < 8; i++) {
        unsafeAtomicAdd(dst + i, bf16_to_f32(s.us[i]) * v);   // global_atomic_add_f32
    }
}

// ---------------- Stage 4: in-place fp32 ReLU ---------------------------------------------
__global__ __launch_bounds__(256) void relu_kernel(float4* __restrict__ out, int n4) {
    int i = blockIdx.x * 256 + threadIdx.x;
    if (i >= n4) return;
    float4 a = out[i];
    a.x = fmaxf(a.x, 0.f); a.y = fmaxf(a.y, 0.f);
    a.z = fmaxf(a.z, 0.f); a.w = fmaxf(a.w, 0.f);
    out[i] = a;
}

extern "C" void kernel_launch(void* const* d_in, const int* in_sizes, int n_in,
                              void* d_out, int out_size, void* d_ws, size_t ws_size,
                              hipStream_t stream) {
    (void)in_sizes; (void)n_in; (void)out_size; (void)ws_size;
    const float* feat     = (const float*)d_in[0];
    const float* W        = (const float*)d_in[1];
    const float* edge_val = (const float*)d_in[2];
    const int*   edge_row = (const int*)d_in[3];
    const int*   edge_col = (const int*)d_in[4];

    ushort* support = (ushort*)d_ws;          // 100000*128 bf16 = 25.6 MB
    float*  out     = (float*)d_out;          // fp32, 51.2 MB

    const int n4 = N_NODES * D / 4;           // d_out as float4s

    zero_kernel<<<(n4 + 255) / 256, 256, 0, stream>>>((float4*)out, n4);
    gemm_kernel<<<(N_NODES + 63) / 64, 256, 0, stream>>>(feat, W, support);
    spmm_kernel<<<(int)(((long)N_EDGES * 16 + 255) / 256), 256, 0, stream>>>(
        support, edge_val, edge_row, edge_col, out);
    relu_kernel<<<(n4 + 255) / 256, 256, 0, stream>>>((float4*)out, n4);
}

// Round 4
// 543.327 us; speedup vs baseline: 10.5206x; 10.5206x over previous
//
#include <hip/hip_runtime.h>
#include <hip/hip_bf16.h>

// GraphConv: out = relu( scatter_add_{edges}( edge_val * (feat @ W)[edge_col] -> edge_row ) )
// Dtypes: feat/W/edge_val = float32, edge_row/col = int32, OUTPUT = float32 (R3 verified PASS).
//
// R3 post-mortem: spmm atomic path = 5578us, WRITE_SIZE 6.55 GB (205M scalar fp32 atomics,
// ~32B HBM write-through each), VALUBusy 0.5% -> atomic-serialization bound.
// R4: device-built CSR (counting sort by edge_row) -> per-row register accumulation,
// each output element written exactly once, ReLU fused. No fp32 atomics at all.
//
// Pipeline: zero(counts/cursor) -> gemm -> hist -> scan -> scatter -> accum(+relu)
// ws: support bf16 25.6MB | offsets 400KB | counts 400KB | cursor 400KB | scol 6.4MB | sval 6.4MB
//     = 39.6 MB. Fallback to R3 atomic path if ws_size too small (constant per session).

#define N_NODES 100000
#define N_EDGES 1600000
#define D 128

typedef __attribute__((ext_vector_type(8))) short short8;
typedef __attribute__((ext_vector_type(4))) float floatx4;

union U16B { uint4 u4; short8 s8; uint u[4]; ushort us[8]; };

__device__ __forceinline__ ushort f32_to_bf16(float f) {
    uint b = __float_as_uint(f);
    return (ushort)((b + 0x7FFFu + ((b >> 16) & 1u)) >> 16);   // RNE; inputs finite
}
__device__ __forceinline__ float bf16_to_f32(ushort u) {
    return __uint_as_float((uint)u << 16);
}

// ---------------- zero an int array (counts + cursor in one go) ---------------------------
__global__ __launch_bounds__(256) void zero_int_kernel(int* __restrict__ p, int n) {
    int i = blockIdx.x * 256 + threadIdx.x;
    if (i < n) p[i] = 0;
}

// ---------------- Stage: support = bf16( fp32 feat @ fp32 W ) via MFMA --------------------
// 4 waves/block, wave owns 16 rows x 128 cols. A-frag: row m=lane&15, quad g=lane>>4 holds k=g*8+j.
// W repacked to fragment-linear bf16 LDS: (k,n) -> Bp[((k>>3)*128+n)*8 + (k&7)].
__global__ __launch_bounds__(256) void gemm_kernel(const float* __restrict__ feat,
                                                   const float* __restrict__ W,
                                                   ushort* __restrict__ support) {
    __shared__ ushort Bp[D * D];   // 32 KB
    const int tid = threadIdx.x;
    for (int e = tid; e < D * D; e += 256) {
        int k = e >> 7, n = e & 127;
        Bp[(((k >> 3) * D + n) << 3) | (k & 7)] = f32_to_bf16(W[e]);
    }
    __syncthreads();

    const int wave = tid >> 6, lane = tid & 63;
    const int row0 = blockIdx.x * 64 + wave * 16;
    if (row0 >= N_NODES) return;              // wave-uniform, after barrier

    const int m = lane & 15, g = lane >> 4;
    floatx4 acc[8];
    const floatx4 z = {0.f, 0.f, 0.f, 0.f};
    #pragma unroll
    for (int t = 0; t < 8; t++) acc[t] = z;

    const float* arow = feat + (size_t)(row0 + m) * D;
    #pragma unroll
    for (int s = 0; s < 4; s++) {             // k-steps of 32
        float4 a0 = *(const float4*)(arow + s * 32 + g * 8);
        float4 a1 = *(const float4*)(arow + s * 32 + g * 8 + 4);
        U16B a;
        a.us[0] = f32_to_bf16(a0.x); a.us[1] = f32_to_bf16(a0.y);
        a.us[2] = f32_to_bf16(a0.z); a.us[3] = f32_to_bf16(a0.w);
        a.us[4] = f32_to_bf16(a1.x); a.us[5] = f32_to_bf16(a1.y);
        a.us[6] = f32_to_bf16(a1.z); a.us[7] = f32_to_bf16(a1.w);
        #pragma unroll
        for (int t = 0; t < 8; t++) {         // 8 col-tiles of 16
            const int chunk = (s * 4 + g) * D + t * 16 + m;
            U16B b; b.u4 = *(const uint4*)(Bp + chunk * 8);
            acc[t] = __builtin_amdgcn_mfma_f32_16x16x32_bf16(a.s8, b.s8, acc[t], 0, 0, 0);
        }
    }
    // C/D: col = lane&15, row = (lane>>4)*4 + reg  (m89-verified)
    #pragma unroll
    for (int t = 0; t < 8; t++) {
        #pragma unroll
        for (int r = 0; r < 4; r++) {
            const int row = row0 + g * 4 + r;
            const int col = t * 16 + m;
            support[(size_t)row * D + col] = f32_to_bf16(acc[t][r]);
        }
    }
}

// ---------------- CSR build: histogram ----------------------------------------------------
__global__ __launch_bounds__(256) void hist_kernel(const int* __restrict__ edge_row,
                                                   int* __restrict__ counts) {
    int e = blockIdx.x * 256 + threadIdx.x;
    if (e < N_EDGES) atomicAdd(&counts[edge_row[e]], 1);
}

// ---------------- CSR build: exclusive prefix sum (single 1024-thread block) --------------
__global__ __launch_bounds__(1024) void scan_kernel(const int* __restrict__ counts,
                                                    int* __restrict__ offsets) {
    __shared__ int s[1024];
    __shared__ int s_running;
    const int tid = threadIdx.x;
    if (tid == 0) s_running = 0;
    __syncthreads();
    for (int base = 0; base < N_NODES; base += 1024) {
        const int i = base + tid;
        const int c = (i < N_NODES) ? counts[i] : 0;
        s[tid] = c;
        __syncthreads();
        #pragma unroll
        for (int d = 1; d < 1024; d <<= 1) {   // Hillis-Steele inclusive scan
            int t = (tid >= d) ? s[tid - d] : 0;
            __syncthreads();
            s[tid] += t;
            __syncthreads();
        }
        const int run = s_running;
        if (i < N_NODES) offsets[i] = run + s[tid] - c;   // exclusive
        __syncthreads();
        if (tid == 1023) s_running = run + s[1023];
        __syncthreads();
    }
    if (tid == 0) offsets[N_NODES] = s_running;           // == N_EDGES
}

// ---------------- CSR build: scatter edges into row-sorted order --------------------------
__global__ __launch_bounds__(256) void scatter_kernel(const int* __restrict__ edge_row,
                                                      const int* __restrict__ edge_col,
                                                      const float* __restrict__ edge_val,
                                                      const int* __restrict__ offsets,
                                                      int* __restrict__ cursor,
                                                      int* __restrict__ scol,
                                                      float* __restrict__ sval) {
    int e = blockIdx.x * 256 + threadIdx.x;
    if (e >= N_EDGES) return;
    const int r = edge_row[e];
    const int p = offsets[r] + atomicAdd(&cursor[r], 1);  // order within row irrelevant (sum)
    scol[p] = edge_col[e];
    sval[p] = edge_val[e];
}

// ---------------- Accumulate: 16 lanes per row, register fp32 accum, fused ReLU -----------
__global__ __launch_bounds__(256) void accum_kernel(const ushort* __restrict__ support,
                                                    const int* __restrict__ offsets,
                                                    const int* __restrict__ scol,
                                                    const float* __restrict__ sval,
                                                    float* __restrict__ out) {
    const int tid = threadIdx.x;
    const int row  = (blockIdx.x * 256 + tid) >> 4;       // one 16-lane group per row
    const int part = tid & 15;
    if (row >= N_NODES) return;

    const int start = offsets[row], end = offsets[row + 1];
    float acc[8];
    #pragma unroll
    for (int i = 0; i < 8; i++) acc[i] = 0.f;

    // 2-stage software pipeline: next (col,val) loads overlap current gather+FMA
    int e = start;
    int c = 0; float v = 0.f;
    if (e < end) { c = scol[e]; v = sval[e]; }
    while (e < end) {
        U16B s; s.u4 = *(const uint4*)(support + (size_t)c * D + part * 8);
        int cn = 0; float vn = 0.f;
        if (e + 1 < end) { cn = scol[e + 1]; vn = sval[e + 1]; }
        #pragma unroll
        for (int i = 0; i < 8; i++) acc[i] += bf16_to_f32(s.us[i]) * v;
        c = cn; v = vn; ++e;
    }

    float4 lo, hi;
    lo.x = fmaxf(acc[0], 0.f); lo.y = fmaxf(acc[1], 0.f);
    lo.z = fmaxf(acc[2], 0.f); lo.w = fmaxf(acc[3], 0.f);
    hi.x = fmaxf(acc[4], 0.f); hi.y = fmaxf(acc[5], 0.f);
    hi.z = fmaxf(acc[6], 0.f); hi.w = fmaxf(acc[7], 0.f);
    float* dst = out + (size_t)row * D + part * 8;
    *(float4*)dst = lo;
    *(float4*)(dst + 4) = hi;
}

// ================= Fallback path (R3 atomic spmm) if ws too small =========================
__global__ __launch_bounds__(256) void zero_f4_kernel(float4* __restrict__ acc, int n4) {
    int i = blockIdx.x * 256 + threadIdx.x;
    if (i < n4) acc[i] = make_float4(0.f, 0.f, 0.f, 0.f);
}
__global__ __launch_bounds__(256) void spmm_kernel(const ushort* __restrict__ support,
                                                   const float* __restrict__ edge_val,
                                                   const int* __restrict__ edge_row,
                                                   const int* __restrict__ edge_col,
                                                   float* __restrict__ out) {
    const long gtid = (long)blockIdx.x * 256 + threadIdx.x;
    const int edge = (int)(gtid >> 4);
    const int part = (int)(gtid & 15);
    if (edge >= N_EDGES) return;
    const int col = edge_col[edge];
    const int row = edge_row[edge];
    const float v = edge_val[edge];
    U16B s; s.u4 = *(const uint4*)(support + (size_t)col * D + part * 8);
    float* dst = out + (size_t)row * D + part * 8;
    #pragma unroll
    for (int i = 0; i < 8; i++) unsafeAtomicAdd(dst + i, bf16_to_f32(s.us[i]) * v);
}
__global__ __launch_bounds__(256) void relu_kernel(float4* __restrict__ out, int n4) {
    int i = blockIdx.x * 256 + threadIdx.x;
    if (i >= n4) return;
    float4 a = out[i];
    a.x = fmaxf(a.x, 0.f); a.y = fmaxf(a.y, 0.f);
    a.z = fmaxf(a.z, 0.f); a.w = fmaxf(a.w, 0.f);
    out[i] = a;
}

extern "C" void kernel_launch(void* const* d_in, const int* in_sizes, int n_in,
                              void* d_out, int out_size, void* d_ws, size_t ws_size,
                              hipStream_t stream) {
    (void)in_sizes; (void)n_in; (void)out_size;
    const float* feat     = (const float*)d_in[0];
    const float* W        = (const float*)d_in[1];
    const float* edge_val = (const float*)d_in[2];
    const int*   edge_row = (const int*)d_in[3];
    const int*   edge_col = (const int*)d_in[4];
    float* out = (float*)d_out;

    // ws layout
    char* ws = (char*)d_ws;
    size_t o = 0;
    ushort* support = (ushort*)(ws + o); o += (size_t)N_NODES * D * sizeof(ushort);  // 25.6 MB
    int*    offsets = (int*)(ws + o);    o += ((size_t)(N_NODES + 1) * 4 + 15) & ~15ull;
    int*    counts  = (int*)(ws + o);    o += (size_t)N_NODES * 4;
    int*    cursor  = (int*)(ws + o);    o += (size_t)N_NODES * 4;
    int*    scol    = (int*)(ws + o);    o += (size_t)N_EDGES * 4;
    float*  sval    = (float*)(ws + o);  o += (size_t)N_EDGES * 4;
    const size_t needed = o;   // ~39.6 MB

    const int eblocks = (N_EDGES + 255) / 256;

    if (ws_size >= needed) {
        // CSR path: no fp32 atomics anywhere
        zero_int_kernel<<<(2 * N_NODES + 255) / 256, 256, 0, stream>>>(counts, 2 * N_NODES); // counts+cursor contiguous
        gemm_kernel<<<(N_NODES + 63) / 64, 256, 0, stream>>>(feat, W, support);
        hist_kernel<<<eblocks, 256, 0, stream>>>(edge_row, counts);
        scan_kernel<<<1, 1024, 0, stream>>>(counts, offsets);
        scatter_kernel<<<eblocks, 256, 0, stream>>>(edge_row, edge_col, edge_val,
                                                    offsets, cursor, scol, sval);
        accum_kernel<<<(N_NODES * 16 + 255) / 256, 256, 0, stream>>>(support, offsets,
                                                                     scol, sval, out);
    } else {
        // R3 fallback: atomic spmm into d_out
        const int n4 = N_NODES * D / 4;
        zero_f4_kernel<<<(n4 + 255) / 256, 256, 0, stream>>>((float4*)out, n4);
        gemm_kernel<<<(N_NODES + 63) / 64, 256, 0, stream>>>(feat, W, support);
        spmm_kernel<<<(int)(((long)N_EDGES * 16 + 255) / 256), 256, 0, stream>>>(
            support, edge_val, edge_row, edge_col, out);
        relu_kernel<<<(n4 + 255) / 256, 256, 0, stream>>>((float4*)out, n4);
    }
}

// Round 5
// 373.562 us; speedup vs baseline: 15.3016x; 1.4544x over previous
//
#include <hip/hip_runtime.h>
#include <hip/hip_bf16.h>

// GraphConv: out = relu( scatter_add_{edges}( edge_val * (feat @ W)[edge_col] -> edge_row ) )
// Dtypes: feat/W/edge_val = float32, edge_row/col = int32, OUTPUT = float32.
//
// R4 post-mortem: CSR path 543us total, but single-block scan_kernel = 179us @ 0.18% occupancy.
// R5: hierarchical multi-block scan (shfl-based), everything else unchanged.
//
// Pipeline: zero(counts/cursor) -> gemm -> hist -> scan1/scan2/scan3 -> scatter -> accum(+relu)

#define N_NODES 100000
#define N_EDGES 1600000
#define D 128
#define SCAN_B 1024
#define SCAN_NB ((N_NODES + SCAN_B - 1) / SCAN_B)   // 98

typedef __attribute__((ext_vector_type(8))) short short8;
typedef __attribute__((ext_vector_type(4))) float floatx4;

union U16B { uint4 u4; short8 s8; uint u[4]; ushort us[8]; };

__device__ __forceinline__ ushort f32_to_bf16(float f) {
    uint b = __float_as_uint(f);
    return (ushort)((b + 0x7FFFu + ((b >> 16) & 1u)) >> 16);   // RNE; inputs finite
}
__device__ __forceinline__ float bf16_to_f32(ushort u) {
    return __uint_as_float((uint)u << 16);
}

// ---------------- zero an int array (counts + cursor in one go) ---------------------------
__global__ __launch_bounds__(256) void zero_int_kernel(int* __restrict__ p, int n) {
    int i = blockIdx.x * 256 + threadIdx.x;
    if (i < n) p[i] = 0;
}

// ---------------- Stage: support = bf16( fp32 feat @ fp32 W ) via MFMA --------------------
__global__ __launch_bounds__(256) void gemm_kernel(const float* __restrict__ feat,
                                                   const float* __restrict__ W,
                                                   ushort* __restrict__ support) {
    __shared__ ushort Bp[D * D];   // 32 KB
    const int tid = threadIdx.x;
    for (int e = tid; e < D * D; e += 256) {
        int k = e >> 7, n = e & 127;
        Bp[(((k >> 3) * D + n) << 3) | (k & 7)] = f32_to_bf16(W[e]);
    }
    __syncthreads();

    const int wave = tid >> 6, lane = tid & 63;
    const int row0 = blockIdx.x * 64 + wave * 16;
    if (row0 >= N_NODES) return;              // wave-uniform, after barrier

    const int m = lane & 15, g = lane >> 4;
    floatx4 acc[8];
    const floatx4 z = {0.f, 0.f, 0.f, 0.f};
    #pragma unroll
    for (int t = 0; t < 8; t++) acc[t] = z;

    const float* arow = feat + (size_t)(row0 + m) * D;
    #pragma unroll
    for (int s = 0; s < 4; s++) {             // k-steps of 32
        float4 a0 = *(const float4*)(arow + s * 32 + g * 8);
        float4 a1 = *(const float4*)(arow + s * 32 + g * 8 + 4);
        U16B a;
        a.us[0] = f32_to_bf16(a0.x); a.us[1] = f32_to_bf16(a0.y);
        a.us[2] = f32_to_bf16(a0.z); a.us[3] = f32_to_bf16(a0.w);
        a.us[4] = f32_to_bf16(a1.x); a.us[5] = f32_to_bf16(a1.y);
        a.us[6] = f32_to_bf16(a1.z); a.us[7] = f32_to_bf16(a1.w);
        #pragma unroll
        for (int t = 0; t < 8; t++) {         // 8 col-tiles of 16
            const int chunk = (s * 4 + g) * D + t * 16 + m;
            U16B b; b.u4 = *(const uint4*)(Bp + chunk * 8);
            acc[t] = __builtin_amdgcn_mfma_f32_16x16x32_bf16(a.s8, b.s8, acc[t], 0, 0, 0);
        }
    }
    // C/D: col = lane&15, row = (lane>>4)*4 + reg  (m89-verified)
    #pragma unroll
    for (int t = 0; t < 8; t++) {
        #pragma unroll
        for (int r = 0; r < 4; r++) {
            const int row = row0 + g * 4 + r;
            const int col = t * 16 + m;
            support[(size_t)row * D + col] = f32_to_bf16(acc[t][r]);
        }
    }
}

// ---------------- CSR build: histogram ----------------------------------------------------
__global__ __launch_bounds__(256) void hist_kernel(const int* __restrict__ edge_row,
                                                   int* __restrict__ counts) {
    int e = blockIdx.x * 256 + threadIdx.x;
    if (e < N_EDGES) atomicAdd(&counts[edge_row[e]], 1);
}

// ---------------- CSR build: hierarchical exclusive scan ----------------------------------
// scan1: per-block exclusive scan (wave shfl + LDS wave-sum combine) + block totals.
__global__ __launch_bounds__(SCAN_B) void scan1_kernel(const int* __restrict__ counts,
                                                       int* __restrict__ offsets,
                                                       int* __restrict__ partials) {
    __shared__ int wsum[SCAN_B / 64];
    const int tid = threadIdx.x;
    const int gid = blockIdx.x * SCAN_B + tid;
    const int lane = tid & 63, wave = tid >> 6;
    const int c = (gid < N_NODES) ? counts[gid] : 0;
    int x = c;                                 // inclusive wave scan
    #pragma unroll
    for (int d = 1; d < 64; d <<= 1) {
        int y = __shfl_up(x, d, 64);
        if (lane >= d) x += y;
    }
    if (lane == 63) wsum[wave] = x;
    __syncthreads();
    if (tid == 0) {                            // serial scan of 16 wave sums
        int run = 0;
        #pragma unroll
        for (int w = 0; w < SCAN_B / 64; w++) { int t = wsum[w]; wsum[w] = run; run += t; }
        partials[blockIdx.x] = run;            // block total
    }
    __syncthreads();
    if (gid < N_NODES) offsets[gid] = x - c + wsum[wave];   // block-local exclusive
}

// scan2: exclusive scan of SCAN_NB (=98) block totals, in place. 2 waves.
__global__ __launch_bounds__(128) void scan2_kernel(int* __restrict__ partials) {
    __shared__ int wsum[2];
    const int tid = threadIdx.x, lane = tid & 63, wave = tid >> 6;
    const int c = (tid < SCAN_NB) ? partials[tid] : 0;
    int x = c;
    #pragma unroll
    for (int d = 1; d < 64; d <<= 1) {
        int y = __shfl_up(x, d, 64);
        if (lane >= d) x += y;
    }
    if (lane == 63) wsum[wave] = x;
    __syncthreads();
    const int base = (wave == 1) ? wsum[0] : 0;
    if (tid < SCAN_NB) partials[tid] = x - c + base;        // exclusive
}

// scan3: add block base; total is compile-time (= N_EDGES).
__global__ __launch_bounds__(SCAN_B) void scan3_kernel(int* __restrict__ offsets,
                                                       const int* __restrict__ partials) {
    const int gid = blockIdx.x * SCAN_B + threadIdx.x;
    if (gid < N_NODES) offsets[gid] += partials[blockIdx.x];
    if (gid == 0) offsets[N_NODES] = N_EDGES;
}

// ---------------- CSR build: scatter edges into row-sorted order --------------------------
__global__ __launch_bounds__(256) void scatter_kernel(const int* __restrict__ edge_row,
                                                      const int* __restrict__ edge_col,
                                                      const float* __restrict__ edge_val,
                                                      const int* __restrict__ offsets,
                                                      int* __restrict__ cursor,
                                                      int* __restrict__ scol,
                                                      float* __restrict__ sval) {
    int e = blockIdx.x * 256 + threadIdx.x;
    if (e >= N_EDGES) return;
    const int r = edge_row[e];
    const int p = offsets[r] + atomicAdd(&cursor[r], 1);  // order within row irrelevant (sum)
    scol[p] = edge_col[e];
    sval[p] = edge_val[e];
}

// ---------------- Accumulate: 16 lanes per row, register fp32 accum, fused ReLU -----------
__global__ __launch_bounds__(256) void accum_kernel(const ushort* __restrict__ support,
                                                    const int* __restrict__ offsets,
                                                    const int* __restrict__ scol,
                                                    const float* __restrict__ sval,
                                                    float* __restrict__ out) {
    const int tid = threadIdx.x;
    const int row  = (blockIdx.x * 256 + tid) >> 4;       // one 16-lane group per row
    const int part = tid & 15;
    if (row >= N_NODES) return;

    const int start = offsets[row], end = offsets[row + 1];
    float acc[8];
    #pragma unroll
    for (int i = 0; i < 8; i++) acc[i] = 0.f;

    int e = start;
    int c = 0; float v = 0.f;
    if (e < end) { c = scol[e]; v = sval[e]; }
    while (e < end) {
        U16B s; s.u4 = *(const uint4*)(support + (size_t)c * D + part * 8);
        int cn = 0; float vn = 0.f;
        if (e + 1 < end) { cn = scol[e + 1]; vn = sval[e + 1]; }
        #pragma unroll
        for (int i = 0; i < 8; i++) acc[i] += bf16_to_f32(s.us[i]) * v;
        c = cn; v = vn; ++e;
    }

    float4 lo, hi;
    lo.x = fmaxf(acc[0], 0.f); lo.y = fmaxf(acc[1], 0.f);
    lo.z = fmaxf(acc[2], 0.f); lo.w = fmaxf(acc[3], 0.f);
    hi.x = fmaxf(acc[4], 0.f); hi.y = fmaxf(acc[5], 0.f);
    hi.z = fmaxf(acc[6], 0.f); hi.w = fmaxf(acc[7], 0.f);
    float* dst = out + (size_t)row * D + part * 8;
    *(float4*)dst = lo;
    *(float4*)(dst + 4) = hi;
}

// ================= Fallback path (R3 atomic spmm) if ws too small =========================
__global__ __launch_bounds__(256) void zero_f4_kernel(float4* __restrict__ acc, int n4) {
    int i = blockIdx.x * 256 + threadIdx.x;
    if (i < n4) acc[i] = make_float4(0.f, 0.f, 0.f, 0.f);
}
__global__ __launch_bounds__(256) void spmm_kernel(const ushort* __restrict__ support,
                                                   const float* __restrict__ edge_val,
                                                   const int* __restrict__ edge_row,
                                                   const int* __restrict__ edge_col,
                                                   float* __restrict__ out) {
    const long gtid = (long)blockIdx.x * 256 + threadIdx.x;
    const int edge = (int)(gtid >> 4);
    const int part = (int)(gtid & 15);
    if (edge >= N_EDGES) return;
    const int col = edge_col[edge];
    const int row = edge_row[edge];
    const float v = edge_val[edge];
    U16B s; s.u4 = *(const uint4*)(support + (size_t)col * D + part * 8);
    float* dst = out + (size_t)row * D + part * 8;
    #pragma unroll
    for (int i = 0; i < 8; i++) unsafeAtomicAdd(dst + i, bf16_to_f32(s.us[i]) * v);
}
__global__ __launch_bounds__(256) void relu_kernel(float4* __restrict__ out, int n4) {
    int i = blockIdx.x * 256 + threadIdx.x;
    if (i >= n4) return;
    float4 a = out[i];
    a.x = fmaxf(a.x, 0.f); a.y = fmaxf(a.y, 0.f);
    a.z = fmaxf(a.z, 0.f); a.w = fmaxf(a.w, 0.f);
    out[i] = a;
}

extern "C" void kernel_launch(void* const* d_in, const int* in_sizes, int n_in,
                              void* d_out, int out_size, void* d_ws, size_t ws_size,
                              hipStream_t stream) {
    (void)in_sizes; (void)n_in; (void)out_size;
    const float* feat     = (const float*)d_in[0];
    const float* W        = (const float*)d_in[1];
    const float* edge_val = (const float*)d_in[2];
    const int*   edge_row = (const int*)d_in[3];
    const int*   edge_col = (const int*)d_in[4];
    float* out = (float*)d_out;

    // ws layout
    char* ws = (char*)d_ws;
    size_t o = 0;
    ushort* support = (ushort*)(ws + o); o += (size_t)N_NODES * D * sizeof(ushort);  // 25.6 MB
    int*    offsets = (int*)(ws + o);    o += ((size_t)(N_NODES + 1) * 4 + 15) & ~15ull;
    int*    counts  = (int*)(ws + o);    o += (size_t)N_NODES * 4;
    int*    cursor  = (int*)(ws + o);    o += (size_t)N_NODES * 4;
    int*    partials= (int*)(ws + o);    o += ((size_t)SCAN_NB * 4 + 15) & ~15ull;
    int*    scol    = (int*)(ws + o);    o += (size_t)N_EDGES * 4;
    float*  sval    = (float*)(ws + o);  o += (size_t)N_EDGES * 4;
    const size_t needed = o;   // ~39.6 MB

    const int eblocks = (N_EDGES + 255) / 256;

    if (ws_size >= needed) {
        // CSR path: no fp32 atomics anywhere
        zero_int_kernel<<<(2 * N_NODES + 255) / 256, 256, 0, stream>>>(counts, 2 * N_NODES);
        gemm_kernel<<<(N_NODES + 63) / 64, 256, 0, stream>>>(feat, W, support);
        hist_kernel<<<eblocks, 256, 0, stream>>>(edge_row, counts);
        scan1_kernel<<<SCAN_NB, SCAN_B, 0, stream>>>(counts, offsets, partials);
        scan2_kernel<<<1, 128, 0, stream>>>(partials);
        scan3_kernel<<<SCAN_NB, SCAN_B, 0, stream>>>(offsets, partials);
        scatter_kernel<<<eblocks, 256, 0, stream>>>(edge_row, edge_col, edge_val,
                                                    offsets, cursor, scol, sval);
        accum_kernel<<<(N_NODES * 16 + 255) / 256, 256, 0, stream>>>(support, offsets,
                                                                     scol, sval, out);
    } else {
        // R3 fallback: atomic spmm into d_out
        const int n4 = N_NODES * D / 4;
        zero_f4_kernel<<<(n4 + 255) / 256, 256, 0, stream>>>((float4*)out, n4);
        gemm_kernel<<<(N_NODES + 63) / 64, 256, 0, stream>>>(feat, W, support);
        spmm_kernel<<<(int)(((long)N_EDGES * 16 + 255) / 256), 256, 0, stream>>>(
            support, edge_val, edge_row, edge_col, out);
        relu_kernel<<<(n4 + 255) / 256, 256, 0, stream>>>((float4*)out, n4);
    }
}

// Round 6
// 343.472 us; speedup vs baseline: 16.6421x; 1.0876x over previous
//
#include <hip/hip_runtime.h>
#include <hip/hip_bf16.h>

// GraphConv: out = relu( scatter_add_{edges}( edge_val * (feat @ W)[edge_col] -> edge_row ) )
// Dtypes: feat/W/edge_val = float32, edge_row/col = int32, OUTPUT = float32.
//
// R5 post-mortem: scatter_kernel 113us, WRITE_SIZE 158MB for 12.8MB payload (12x write
// amplification: two 4B random stores/edge to separate arrays).
// R6: pack (col,val) into one int2 array 'epack' -> one 8B random store/edge, 2x line fill
// density, accum reads one 8B broadcast. Everything else unchanged.

#define N_NODES 100000
#define N_EDGES 1600000
#define D 128
#define SCAN_B 1024
#define SCAN_NB ((N_NODES + SCAN_B - 1) / SCAN_B)   // 98

typedef __attribute__((ext_vector_type(8))) short short8;
typedef __attribute__((ext_vector_type(4))) float floatx4;

union U16B { uint4 u4; short8 s8; uint u[4]; ushort us[8]; };

__device__ __forceinline__ ushort f32_to_bf16(float f) {
    uint b = __float_as_uint(f);
    return (ushort)((b + 0x7FFFu + ((b >> 16) & 1u)) >> 16);   // RNE; inputs finite
}
__device__ __forceinline__ float bf16_to_f32(ushort u) {
    return __uint_as_float((uint)u << 16);
}

// ---------------- zero an int array (counts + cursor in one go) ---------------------------
__global__ __launch_bounds__(256) void zero_int_kernel(int* __restrict__ p, int n) {
    int i = blockIdx.x * 256 + threadIdx.x;
    if (i < n) p[i] = 0;
}

// ---------------- Stage: support = bf16( fp32 feat @ fp32 W ) via MFMA --------------------
__global__ __launch_bounds__(256) void gemm_kernel(const float* __restrict__ feat,
                                                   const float* __restrict__ W,
                                                   ushort* __restrict__ support) {
    __shared__ ushort Bp[D * D];   // 32 KB
    const int tid = threadIdx.x;
    for (int e = tid; e < D * D; e += 256) {
        int k = e >> 7, n = e & 127;
        Bp[(((k >> 3) * D + n) << 3) | (k & 7)] = f32_to_bf16(W[e]);
    }
    __syncthreads();

    const int wave = tid >> 6, lane = tid & 63;
    const int row0 = blockIdx.x * 64 + wave * 16;
    if (row0 >= N_NODES) return;              // wave-uniform, after barrier

    const int m = lane & 15, g = lane >> 4;
    floatx4 acc[8];
    const floatx4 z = {0.f, 0.f, 0.f, 0.f};
    #pragma unroll
    for (int t = 0; t < 8; t++) acc[t] = z;

    const float* arow = feat + (size_t)(row0 + m) * D;
    #pragma unroll
    for (int s = 0; s < 4; s++) {             // k-steps of 32
        float4 a0 = *(const float4*)(arow + s * 32 + g * 8);
        float4 a1 = *(const float4*)(arow + s * 32 + g * 8 + 4);
        U16B a;
        a.us[0] = f32_to_bf16(a0.x); a.us[1] = f32_to_bf16(a0.y);
        a.us[2] = f32_to_bf16(a0.z); a.us[3] = f32_to_bf16(a0.w);
        a.us[4] = f32_to_bf16(a1.x); a.us[5] = f32_to_bf16(a1.y);
        a.us[6] = f32_to_bf16(a1.z); a.us[7] = f32_to_bf16(a1.w);
        #pragma unroll
        for (int t = 0; t < 8; t++) {         // 8 col-tiles of 16
            const int chunk = (s * 4 + g) * D + t * 16 + m;
            U16B b; b.u4 = *(const uint4*)(Bp + chunk * 8);
            acc[t] = __builtin_amdgcn_mfma_f32_16x16x32_bf16(a.s8, b.s8, acc[t], 0, 0, 0);
        }
    }
    // C/D: col = lane&15, row = (lane>>4)*4 + reg  (m89-verified)
    #pragma unroll
    for (int t = 0; t < 8; t++) {
        #pragma unroll
        for (int r = 0; r < 4; r++) {
            const int row = row0 + g * 4 + r;
            const int col = t * 16 + m;
            support[(size_t)row * D + col] = f32_to_bf16(acc[t][r]);
        }
    }
}

// ---------------- CSR build: histogram ----------------------------------------------------
__global__ __launch_bounds__(256) void hist_kernel(const int* __restrict__ edge_row,
                                                   int* __restrict__ counts) {
    int e = blockIdx.x * 256 + threadIdx.x;
    if (e < N_EDGES) atomicAdd(&counts[edge_row[e]], 1);
}

// ---------------- CSR build: hierarchical exclusive scan ----------------------------------
__global__ __launch_bounds__(SCAN_B) void scan1_kernel(const int* __restrict__ counts,
                                                       int* __restrict__ offsets,
                                                       int* __restrict__ partials) {
    __shared__ int wsum[SCAN_B / 64];
    const int tid = threadIdx.x;
    const int gid = blockIdx.x * SCAN_B + tid;
    const int lane = tid & 63, wave = tid >> 6;
    const int c = (gid < N_NODES) ? counts[gid] : 0;
    int x = c;                                 // inclusive wave scan
    #pragma unroll
    for (int d = 1; d < 64; d <<= 1) {
        int y = __shfl_up(x, d, 64);
        if (lane >= d) x += y;
    }
    if (lane == 63) wsum[wave] = x;
    __syncthreads();
    if (tid == 0) {                            // serial scan of 16 wave sums
        int run = 0;
        #pragma unroll
        for (int w = 0; w < SCAN_B / 64; w++) { int t = wsum[w]; wsum[w] = run; run += t; }
        partials[blockIdx.x] = run;            // block total
    }
    __syncthreads();
    if (gid < N_NODES) offsets[gid] = x - c + wsum[wave];   // block-local exclusive
}

__global__ __launch_bounds__(128) void scan2_kernel(int* __restrict__ partials) {
    __shared__ int wsum[2];
    const int tid = threadIdx.x, lane = tid & 63, wave = tid >> 6;
    const int c = (tid < SCAN_NB) ? partials[tid] : 0;
    int x = c;
    #pragma unroll
    for (int d = 1; d < 64; d <<= 1) {
        int y = __shfl_up(x, d, 64);
        if (lane >= d) x += y;
    }
    if (lane == 63) wsum[wave] = x;
    __syncthreads();
    const int base = (wave == 1) ? wsum[0] : 0;
    if (tid < SCAN_NB) partials[tid] = x - c + base;        // exclusive
}

__global__ __launch_bounds__(SCAN_B) void scan3_kernel(int* __restrict__ offsets,
                                                       const int* __restrict__ partials) {
    const int gid = blockIdx.x * SCAN_B + threadIdx.x;
    if (gid < N_NODES) offsets[gid] += partials[blockIdx.x];
    if (gid == 0) offsets[N_NODES] = N_EDGES;
}

// ---------------- CSR build: scatter edges, ONE packed 8B store per edge ------------------
__global__ __launch_bounds__(256) void scatter_kernel(const int* __restrict__ edge_row,
                                                      const int* __restrict__ edge_col,
                                                      const float* __restrict__ edge_val,
                                                      const int* __restrict__ offsets,
                                                      int* __restrict__ cursor,
                                                      int2* __restrict__ epack) {
    int e = blockIdx.x * 256 + threadIdx.x;
    if (e >= N_EDGES) return;
    const int r = edge_row[e];
    const int p = offsets[r] + atomicAdd(&cursor[r], 1);  // order within row irrelevant (sum)
    int2 pk;
    pk.x = edge_col[e];
    pk.y = __float_as_int(edge_val[e]);
    epack[p] = pk;
}

// ---------------- Accumulate: 16 lanes per row, register fp32 accum, fused ReLU -----------
__global__ __launch_bounds__(256) void accum_kernel(const ushort* __restrict__ support,
                                                    const int* __restrict__ offsets,
                                                    const int2* __restrict__ epack,
                                                    float* __restrict__ out) {
    const int tid = threadIdx.x;
    const int row  = (blockIdx.x * 256 + tid) >> 4;       // one 16-lane group per row
    const int part = tid & 15;
    if (row >= N_NODES) return;

    const int start = offsets[row], end = offsets[row + 1];
    float acc[8];
    #pragma unroll
    for (int i = 0; i < 8; i++) acc[i] = 0.f;

    int e = start;
    int2 pk = make_int2(0, 0);
    if (e < end) pk = epack[e];
    while (e < end) {
        const int   c = pk.x;
        const float v = __int_as_float(pk.y);
        U16B s; s.u4 = *(const uint4*)(support + (size_t)c * D + part * 8);
        int2 pn = make_int2(0, 0);
        if (e + 1 < end) pn = epack[e + 1];
        #pragma unroll
        for (int i = 0; i < 8; i++) acc[i] += bf16_to_f32(s.us[i]) * v;
        pk = pn; ++e;
    }

    float4 lo, hi;
    lo.x = fmaxf(acc[0], 0.f); lo.y = fmaxf(acc[1], 0.f);
    lo.z = fmaxf(acc[2], 0.f); lo.w = fmaxf(acc[3], 0.f);
    hi.x = fmaxf(acc[4], 0.f); hi.y = fmaxf(acc[5], 0.f);
    hi.z = fmaxf(acc[6], 0.f); hi.w = fmaxf(acc[7], 0.f);
    float* dst = out + (size_t)row * D + part * 8;
    *(float4*)dst = lo;
    *(float4*)(dst + 4) = hi;
}

// ================= Fallback path (R3 atomic spmm) if ws too small =========================
__global__ __launch_bounds__(256) void zero_f4_kernel(float4* __restrict__ acc, int n4) {
    int i = blockIdx.x * 256 + threadIdx.x;
    if (i < n4) acc[i] = make_float4(0.f, 0.f, 0.f, 0.f);
}
__global__ __launch_bounds__(256) void spmm_kernel(const ushort* __restrict__ support,
                                                   const float* __restrict__ edge_val,
                                                   const int* __restrict__ edge_row,
                                                   const int* __restrict__ edge_col,
                                                   float* __restrict__ out) {
    const long gtid = (long)blockIdx.x * 256 + threadIdx.x;
    const int edge = (int)(gtid >> 4);
    const int part = (int)(gtid & 15);
    if (edge >= N_EDGES) return;
    const int col = edge_col[edge];
    const int row = edge_row[edge];
    const float v = edge_val[edge];
    U16B s; s.u4 = *(const uint4*)(support + (size_t)col * D + part * 8);
    float* dst = out + (size_t)row * D + part * 8;
    #pragma unroll
    for (int i = 0; i < 8; i++) unsafeAtomicAdd(dst + i, bf16_to_f32(s.us[i]) * v);
}
__global__ __launch_bounds__(256) void relu_kernel(float4* __restrict__ out, int n4) {
    int i = blockIdx.x * 256 + threadIdx.x;
    if (i >= n4) return;
    float4 a = out[i];
    a.x = fmaxf(a.x, 0.f); a.y = fmaxf(a.y, 0.f);
    a.z = fmaxf(a.z, 0.f); a.w = fmaxf(a.w, 0.f);
    out[i] = a;
}

extern "C" void kernel_launch(void* const* d_in, const int* in_sizes, int n_in,
                              void* d_out, int out_size, void* d_ws, size_t ws_size,
                              hipStream_t stream) {
    (void)in_sizes; (void)n_in; (void)out_size;
    const float* feat     = (const float*)d_in[0];
    const float* W        = (const float*)d_in[1];
    const float* edge_val = (const float*)d_in[2];
    const int*   edge_row = (const int*)d_in[3];
    const int*   edge_col = (const int*)d_in[4];
    float* out = (float*)d_out;

    // ws layout
    char* ws = (char*)d_ws;
    size_t o = 0;
    ushort* support = (ushort*)(ws + o); o += (size_t)N_NODES * D * sizeof(ushort);  // 25.6 MB
    int*    offsets = (int*)(ws + o);    o += ((size_t)(N_NODES + 1) * 4 + 15) & ~15ull;
    int*    counts  = (int*)(ws + o);    o += (size_t)N_NODES * 4;
    int*    cursor  = (int*)(ws + o);    o += (size_t)N_NODES * 4;
    int*    partials= (int*)(ws + o);    o += ((size_t)SCAN_NB * 4 + 15) & ~15ull;
    int2*   epack   = (int2*)(ws + o);   o += (size_t)N_EDGES * 8;                   // 12.8 MB
    const size_t needed = o;   // ~39.6 MB

    const int eblocks = (N_EDGES + 255) / 256;

    if (ws_size >= needed) {
        // CSR path: no fp32 atomics anywhere
        zero_int_kernel<<<(2 * N_NODES + 255) / 256, 256, 0, stream>>>(counts, 2 * N_NODES);
        gemm_kernel<<<(N_NODES + 63) / 64, 256, 0, stream>>>(feat, W, support);
        hist_kernel<<<eblocks, 256, 0, stream>>>(edge_row, counts);
        scan1_kernel<<<SCAN_NB, SCAN_B, 0, stream>>>(counts, offsets, partials);
        scan2_kernel<<<1, 128, 0, stream>>>(partials);
        scan3_kernel<<<SCAN_NB, SCAN_B, 0, stream>>>(offsets, partials);
        scatter_kernel<<<eblocks, 256, 0, stream>>>(edge_row, edge_col, edge_val,
                                                    offsets, cursor, epack);
        accum_kernel<<<(N_NODES * 16 + 255) / 256, 256, 0, stream>>>(support, offsets,
                                                                     epack, out);
    } else {
        // R3 fallback: atomic spmm into d_out
        const int n4 = N_NODES * D / 4;
        zero_f4_kernel<<<(n4 + 255) / 256, 256, 0, stream>>>((float4*)out, n4);
        gemm_kernel<<<(N_NODES + 63) / 64, 256, 0, stream>>>(feat, W, support);
        spmm_kernel<<<(int)(((long)N_EDGES * 16 + 255) / 256), 256, 0, stream>>>(
            support, edge_val, edge_row, edge_col, out);
        relu_kernel<<<(n4 + 255) / 256, 256, 0, stream>>>((float4*)out, n4);
    }
}

// Round 8
// 322.738 us; speedup vs baseline: 17.7113x; 1.0642x over previous
//
#include <hip/hip_runtime.h>
#include <hip/hip_bf16.h>

// GraphConv: out = relu( scatter_add_{edges}( edge_val * (feat @ W)[edge_col] -> edge_row ) )
// Dtypes: feat/W/edge_val = float32, edge_row/col = int32, OUTPUT = float32.
//
// R6 post-mortem: scatter 91us, WRITE_SIZE 101MB = 1.6M x 64B -> every random 8B store
// writes back a full line (cross-XCD line bounce, per-XCD L2 non-coherent).
// R7/R8: (a) rank computed inside hist (atomicAdd returns it) -> scatter loses its atomic
//     RMW dependency; (b) nt stores for epack + out (no-reuse streams, keep L2/L3 for
//     support gather); (c) accum 2-wide unroll with dual accumulator banks.
// R8 fix: __builtin_nontemporal_store needs clang ext_vector types, not HIP_vector_type.

#define N_NODES 100000
#define N_EDGES 1600000
#define D 128
#define SCAN_B 1024
#define SCAN_NB ((N_NODES + SCAN_B - 1) / SCAN_B)   // 98

typedef __attribute__((ext_vector_type(8))) short short8;
typedef __attribute__((ext_vector_type(4))) float floatx4;
typedef int  iv2 __attribute__((ext_vector_type(2)));   // nt-store-compatible int2
typedef float fv4 __attribute__((ext_vector_type(4)));  // nt-store-compatible float4

union U16B { uint4 u4; short8 s8; uint u[4]; ushort us[8]; };

__device__ __forceinline__ ushort f32_to_bf16(float f) {
    uint b = __float_as_uint(f);
    return (ushort)((b + 0x7FFFu + ((b >> 16) & 1u)) >> 16);   // RNE; inputs finite
}
__device__ __forceinline__ float bf16_to_f32(ushort u) {
    return __uint_as_float((uint)u << 16);
}

// ---------------- zero counts ---------------------------------------------------------------
__global__ __launch_bounds__(256) void zero_int_kernel(int* __restrict__ p, int n) {
    int i = blockIdx.x * 256 + threadIdx.x;
    if (i < n) p[i] = 0;
}

// ---------------- Stage: support = bf16( fp32 feat @ fp32 W ) via MFMA ----------------------
__global__ __launch_bounds__(256) void gemm_kernel(const float* __restrict__ feat,
                                                   const float* __restrict__ W,
                                                   ushort* __restrict__ support) {
    __shared__ ushort Bp[D * D];   // 32 KB
    const int tid = threadIdx.x;
    for (int e = tid; e < D * D; e += 256) {
        int k = e >> 7, n = e & 127;
        Bp[(((k >> 3) * D + n) << 3) | (k & 7)] = f32_to_bf16(W[e]);
    }
    __syncthreads();

    const int wave = tid >> 6, lane = tid & 63;
    const int row0 = blockIdx.x * 64 + wave * 16;
    if (row0 >= N_NODES) return;              // wave-uniform, after barrier

    const int m = lane & 15, g = lane >> 4;
    floatx4 acc[8];
    const floatx4 z = {0.f, 0.f, 0.f, 0.f};
    #pragma unroll
    for (int t = 0; t < 8; t++) acc[t] = z;

    const float* arow = feat + (size_t)(row0 + m) * D;
    #pragma unroll
    for (int s = 0; s < 4; s++) {             // k-steps of 32
        float4 a0 = *(const float4*)(arow + s * 32 + g * 8);
        float4 a1 = *(const float4*)(arow + s * 32 + g * 8 + 4);
        U16B a;
        a.us[0] = f32_to_bf16(a0.x); a.us[1] = f32_to_bf16(a0.y);
        a.us[2] = f32_to_bf16(a0.z); a.us[3] = f32_to_bf16(a0.w);
        a.us[4] = f32_to_bf16(a1.x); a.us[5] = f32_to_bf16(a1.y);
        a.us[6] = f32_to_bf16(a1.z); a.us[7] = f32_to_bf16(a1.w);
        #pragma unroll
        for (int t = 0; t < 8; t++) {         // 8 col-tiles of 16
            const int chunk = (s * 4 + g) * D + t * 16 + m;
            U16B b; b.u4 = *(const uint4*)(Bp + chunk * 8);
            acc[t] = __builtin_amdgcn_mfma_f32_16x16x32_bf16(a.s8, b.s8, acc[t], 0, 0, 0);
        }
    }
    // C/D: col = lane&15, row = (lane>>4)*4 + reg  (m89-verified)
    #pragma unroll
    for (int t = 0; t < 8; t++) {
        #pragma unroll
        for (int r = 0; r < 4; r++) {
            const int row = row0 + g * 4 + r;
            const int col = t * 16 + m;
            support[(size_t)row * D + col] = f32_to_bf16(acc[t][r]);
        }
    }
}

// ---------------- CSR build: histogram + per-edge rank (atomic returns it free) -------------
__global__ __launch_bounds__(256) void hist_kernel(const int* __restrict__ edge_row,
                                                   int* __restrict__ counts,
                                                   int* __restrict__ rank) {
    int e = blockIdx.x * 256 + threadIdx.x;
    if (e < N_EDGES) rank[e] = atomicAdd(&counts[edge_row[e]], 1);
}

// ---------------- CSR build: hierarchical exclusive scan ------------------------------------
__global__ __launch_bounds__(SCAN_B) void scan1_kernel(const int* __restrict__ counts,
                                                       int* __restrict__ offsets,
                                                       int* __restrict__ partials) {
    __shared__ int wsum[SCAN_B / 64];
    const int tid = threadIdx.x;
    const int gid = blockIdx.x * SCAN_B + tid;
    const int lane = tid & 63, wave = tid >> 6;
    const int c = (gid < N_NODES) ? counts[gid] : 0;
    int x = c;                                 // inclusive wave scan
    #pragma unroll
    for (int d = 1; d < 64; d <<= 1) {
        int y = __shfl_up(x, d, 64);
        if (lane >= d) x += y;
    }
    if (lane == 63) wsum[wave] = x;
    __syncthreads();
    if (tid == 0) {                            // serial scan of 16 wave sums
        int run = 0;
        #pragma unroll
        for (int w = 0; w < SCAN_B / 64; w++) { int t = wsum[w]; wsum[w] = run; run += t; }
        partials[blockIdx.x] = run;            // block total
    }
    __syncthreads();
    if (gid < N_NODES) offsets[gid] = x - c + wsum[wave];   // block-local exclusive
}

__global__ __launch_bounds__(128) void scan2_kernel(int* __restrict__ partials) {
    __shared__ int wsum[2];
    const int tid = threadIdx.x, lane = tid & 63, wave = tid >> 6;
    const int c = (tid < SCAN_NB) ? partials[tid] : 0;
    int x = c;
    #pragma unroll
    for (int d = 1; d < 64; d <<= 1) {
        int y = __shfl_up(x, d, 64);
        if (lane >= d) x += y;
    }
    if (lane == 63) wsum[wave] = x;
    __syncthreads();
    const int base = (wave == 1) ? wsum[0] : 0;
    if (tid < SCAN_NB) partials[tid] = x - c + base;        // exclusive
}

__global__ __launch_bounds__(SCAN_B) void scan3_kernel(int* __restrict__ offsets,
                                                       const int* __restrict__ partials) {
    const int gid = blockIdx.x * SCAN_B + threadIdx.x;
    if (gid < N_NODES) offsets[gid] += partials[blockIdx.x];
    if (gid == 0) offsets[N_NODES] = N_EDGES;
}

// ---------------- CSR build: scatter (no atomics; one nt 8B store per edge) -----------------
__global__ __launch_bounds__(256) void scatter_kernel(const int* __restrict__ edge_row,
                                                      const int* __restrict__ edge_col,
                                                      const float* __restrict__ edge_val,
                                                      const int* __restrict__ offsets,
                                                      const int* __restrict__ rank,
                                                      iv2* __restrict__ epack) {
    int e = blockIdx.x * 256 + threadIdx.x;
    if (e >= N_EDGES) return;
    const int r = edge_row[e];
    const int p = offsets[r] + rank[e];
    iv2 pk;
    pk.x = edge_col[e];
    pk.y = __float_as_int(edge_val[e]);
    __builtin_nontemporal_store(pk, epack + p);
}

// ---------------- Accumulate: 16 lanes/row, 2-wide unroll, dual acc banks, fused ReLU -------
__global__ __launch_bounds__(256) void accum_kernel(const ushort* __restrict__ support,
                                                    const int* __restrict__ offsets,
                                                    const iv2* __restrict__ epack,
                                                    float* __restrict__ out) {
    const int tid = threadIdx.x;
    const int row  = (blockIdx.x * 256 + tid) >> 4;       // one 16-lane group per row
    const int part = tid & 15;
    if (row >= N_NODES) return;

    const int start = offsets[row], end = offsets[row + 1];
    float acc0[8], acc1[8];
    #pragma unroll
    for (int i = 0; i < 8; i++) { acc0[i] = 0.f; acc1[i] = 0.f; }

    int e = start;
    for (; e + 1 < end; e += 2) {
        const iv2 pa = epack[e];
        const iv2 pb = epack[e + 1];
        U16B sa; sa.u4 = *(const uint4*)(support + (size_t)pa.x * D + part * 8);
        U16B sb; sb.u4 = *(const uint4*)(support + (size_t)pb.x * D + part * 8);
        const float va = __int_as_float(pa.y);
        const float vb = __int_as_float(pb.y);
        #pragma unroll
        for (int i = 0; i < 8; i++) {
            acc0[i] += bf16_to_f32(sa.us[i]) * va;
            acc1[i] += bf16_to_f32(sb.us[i]) * vb;
        }
    }
    if (e < end) {
        const iv2 pa = epack[e];
        U16B sa; sa.u4 = *(const uint4*)(support + (size_t)pa.x * D + part * 8);
        const float va = __int_as_float(pa.y);
        #pragma unroll
        for (int i = 0; i < 8; i++) acc0[i] += bf16_to_f32(sa.us[i]) * va;
    }

    fv4 lo, hi;
    lo.x = fmaxf(acc0[0] + acc1[0], 0.f); lo.y = fmaxf(acc0[1] + acc1[1], 0.f);
    lo.z = fmaxf(acc0[2] + acc1[2], 0.f); lo.w = fmaxf(acc0[3] + acc1[3], 0.f);
    hi.x = fmaxf(acc0[4] + acc1[4], 0.f); hi.y = fmaxf(acc0[5] + acc1[5], 0.f);
    hi.z = fmaxf(acc0[6] + acc1[6], 0.f); hi.w = fmaxf(acc0[7] + acc1[7], 0.f);
    float* dst = out + (size_t)row * D + part * 8;
    __builtin_nontemporal_store(lo, (fv4*)dst);        // out has zero reuse: don't pollute
    __builtin_nontemporal_store(hi, (fv4*)(dst + 4));  // L2/L3 (support gather lives there)
}

// ================= Fallback path (R3 atomic spmm) if ws too small ===========================
__global__ __launch_bounds__(256) void zero_f4_kernel(float4* __restrict__ acc, int n4) {
    int i = blockIdx.x * 256 + threadIdx.x;
    if (i < n4) acc[i] = make_float4(0.f, 0.f, 0.f, 0.f);
}
__global__ __launch_bounds__(256) void spmm_kernel(const ushort* __restrict__ support,
                                                   const float* __restrict__ edge_val,
                                                   const int* __restrict__ edge_row,
                                                   const int* __restrict__ edge_col,
                                                   float* __restrict__ out) {
    const long gtid = (long)blockIdx.x * 256 + threadIdx.x;
    const int edge = (int)(gtid >> 4);
    const int part = (int)(gtid & 15);
    if (edge >= N_EDGES) return;
    const int col = edge_col[edge];
    const int row = edge_row[edge];
    const float v = edge_val[edge];
    U16B s; s.u4 = *(const uint4*)(support + (size_t)col * D + part * 8);
    float* dst = out + (size_t)row * D + part * 8;
    #pragma unroll
    for (int i = 0; i < 8; i++) unsafeAtomicAdd(dst + i, bf16_to_f32(s.us[i]) * v);
}
__global__ __launch_bounds__(256) void relu_kernel(float4* __restrict__ out, int n4) {
    int i = blockIdx.x * 256 + threadIdx.x;
    if (i >= n4) return;
    float4 a = out[i];
    a.x = fmaxf(a.x, 0.f); a.y = fmaxf(a.y, 0.f);
    a.z = fmaxf(a.z, 0.f); a.w = fmaxf(a.w, 0.f);
    out[i] = a;
}

extern "C" void kernel_launch(void* const* d_in, const int* in_sizes, int n_in,
                              void* d_out, int out_size, void* d_ws, size_t ws_size,
                              hipStream_t stream) {
    (void)in_sizes; (void)n_in; (void)out_size;
    const float* feat     = (const float*)d_in[0];
    const float* W        = (const float*)d_in[1];
    const float* edge_val = (const float*)d_in[2];
    const int*   edge_row = (const int*)d_in[3];
    const int*   edge_col = (const int*)d_in[4];
    float* out = (float*)d_out;

    // ws layout
    char* ws = (char*)d_ws;
    size_t o = 0;
    ushort* support = (ushort*)(ws + o); o += (size_t)N_NODES * D * sizeof(ushort);  // 25.6 MB
    int*    offsets = (int*)(ws + o);    o += ((size_t)(N_NODES + 1) * 4 + 15) & ~15ull;
    int*    counts  = (int*)(ws + o);    o += (size_t)N_NODES * 4;
    int*    partials= (int*)(ws + o);    o += ((size_t)SCAN_NB * 4 + 15) & ~15ull;
    int*    rank    = (int*)(ws + o);    o += (size_t)N_EDGES * 4;                   // 6.4 MB
    iv2*    epack   = (iv2*)(ws + o);    o += (size_t)N_EDGES * 8;                   // 12.8 MB
    const size_t needed = o;   // ~45.6 MB

    const int eblocks = (N_EDGES + 255) / 256;

    if (ws_size >= needed) {
        // CSR path: fp32-atomic-free
        zero_int_kernel<<<(N_NODES + 255) / 256, 256, 0, stream>>>(counts, N_NODES);
        gemm_kernel<<<(N_NODES + 63) / 64, 256, 0, stream>>>(feat, W, support);
        hist_kernel<<<eblocks, 256, 0, stream>>>(edge_row, counts, rank);
        scan1_kernel<<<SCAN_NB, SCAN_B, 0, stream>>>(counts, offsets, partials);
        scan2_kernel<<<1, 128, 0, stream>>>(partials);
        scan3_kernel<<<SCAN_NB, SCAN_B, 0, stream>>>(offsets, partials);
        scatter_kernel<<<eblocks, 256, 0, stream>>>(edge_row, edge_col, edge_val,
                                                    offsets, rank, epack);
        accum_kernel<<<(N_NODES * 16 + 255) / 256, 256, 0, stream>>>(support, offsets,
                                                                     epack, out);
    } else {
        // R3 fallback: atomic spmm into d_out
        const int n4 = N_NODES * D / 4;
        zero_f4_kernel<<<(n4 + 255) / 256, 256, 0, stream>>>((float4*)out, n4);
        gemm_kernel<<<(N_NODES + 63) / 64, 256, 0, stream>>>(feat, W, support);
        spmm_kernel<<<(int)(((long)N_EDGES * 16 + 255) / 256), 256, 0, stream>>>(
            support, edge_val, edge_row, edge_col, out);
        relu_kernel<<<(n4 + 255) / 256, 256, 0, stream>>>((float4*)out, n4);
    }
}

// Round 9
// 318.932 us; speedup vs baseline: 17.9227x; 1.0119x over previous
//
#include <hip/hip_runtime.h>
#include <hip/hip_bf16.h>

// GraphConv: out = relu( scatter_add_{edges}( edge_val * (feat @ W)[edge_col] -> edge_row ) )
// Dtypes: feat/W/edge_val = float32, edge_row/col = int32, OUTPUT = float32.
//
// R8 post-mortem: hist 68.6us (WRITE 56MB = counts-line bounce across XCDs, VALU 0.5%),
// accum 68.4us (3.5TB/s, 2 loads in flight).
// R9: (a) 8 XCD-affine count copies (copy = blockIdx&7) -> atomics stay in one XCD's L2;
//     scan1 folds copies into per-copy bases; rank -> ushort (ws stays 45.2MB).
//     (b) accum 4-wide unroll, int4 epack loads (2 edges/load), 2 acc banks.

#define N_NODES 100000
#define N_EDGES 1600000
#define D 128
#define NCOPY 8
#define SCAN_B 1024
#define SCAN_NB ((N_NODES + SCAN_B - 1) / SCAN_B)   // 98

typedef __attribute__((ext_vector_type(8))) short short8;
typedef __attribute__((ext_vector_type(4))) float floatx4;
typedef int  iv2 __attribute__((ext_vector_type(2)));   // nt-store-compatible int2
typedef int  iv4 __attribute__((ext_vector_type(4)));
typedef float fv4 __attribute__((ext_vector_type(4)));  // nt-store-compatible float4

union U16B { uint4 u4; short8 s8; uint u[4]; ushort us[8]; };

__device__ __forceinline__ ushort f32_to_bf16(float f) {
    uint b = __float_as_uint(f);
    return (ushort)((b + 0x7FFFu + ((b >> 16) & 1u)) >> 16);   // RNE; inputs finite
}
__device__ __forceinline__ float bf16_to_f32(ushort u) {
    return __uint_as_float((uint)u << 16);
}

// ---------------- zero counts (8 copies) ----------------------------------------------------
__global__ __launch_bounds__(256) void zero_int_kernel(int* __restrict__ p, int n) {
    int i = blockIdx.x * 256 + threadIdx.x;
    if (i < n) p[i] = 0;
}

// ---------------- Stage: support = bf16( fp32 feat @ fp32 W ) via MFMA ----------------------
__global__ __launch_bounds__(256) void gemm_kernel(const float* __restrict__ feat,
                                                   const float* __restrict__ W,
                                                   ushort* __restrict__ support) {
    __shared__ ushort Bp[D * D];   // 32 KB
    const int tid = threadIdx.x;
    for (int e = tid; e < D * D; e += 256) {
        int k = e >> 7, n = e & 127;
        Bp[(((k >> 3) * D + n) << 3) | (k & 7)] = f32_to_bf16(W[e]);
    }
    __syncthreads();

    const int wave = tid >> 6, lane = tid & 63;
    const int row0 = blockIdx.x * 64 + wave * 16;
    if (row0 >= N_NODES) return;              // wave-uniform, after barrier

    const int m = lane & 15, g = lane >> 4;
    floatx4 acc[8];
    const floatx4 z = {0.f, 0.f, 0.f, 0.f};
    #pragma unroll
    for (int t = 0; t < 8; t++) acc[t] = z;

    const float* arow = feat + (size_t)(row0 + m) * D;
    #pragma unroll
    for (int s = 0; s < 4; s++) {             // k-steps of 32
        float4 a0 = *(const float4*)(arow + s * 32 + g * 8);
        float4 a1 = *(const float4*)(arow + s * 32 + g * 8 + 4);
        U16B a;
        a.us[0] = f32_to_bf16(a0.x); a.us[1] = f32_to_bf16(a0.y);
        a.us[2] = f32_to_bf16(a0.z); a.us[3] = f32_to_bf16(a0.w);
        a.us[4] = f32_to_bf16(a1.x); a.us[5] = f32_to_bf16(a1.y);
        a.us[6] = f32_to_bf16(a1.z); a.us[7] = f32_to_bf16(a1.w);
        #pragma unroll
        for (int t = 0; t < 8; t++) {         // 8 col-tiles of 16
            const int chunk = (s * 4 + g) * D + t * 16 + m;
            U16B b; b.u4 = *(const uint4*)(Bp + chunk * 8);
            acc[t] = __builtin_amdgcn_mfma_f32_16x16x32_bf16(a.s8, b.s8, acc[t], 0, 0, 0);
        }
    }
    // C/D: col = lane&15, row = (lane>>4)*4 + reg  (m89-verified)
    #pragma unroll
    for (int t = 0; t < 8; t++) {
        #pragma unroll
        for (int r = 0; r < 4; r++) {
            const int row = row0 + g * 4 + r;
            const int col = t * 16 + m;
            support[(size_t)row * D + col] = f32_to_bf16(acc[t][r]);
        }
    }
}

// ---------------- CSR build: histogram into 8 XCD-affine copies + per-edge rank -------------
__global__ __launch_bounds__(256) void hist_kernel(const int* __restrict__ edge_row,
                                                   int* __restrict__ counts,   // [NCOPY][N]
                                                   ushort* __restrict__ rank) {
    int e = blockIdx.x * 256 + threadIdx.x;
    if (e >= N_EDGES) return;
    const int copy = blockIdx.x & (NCOPY - 1);   // same mapping recomputed in scatter
    rank[e] = (ushort)atomicAdd(&counts[copy * N_NODES + edge_row[e]], 1);
}

// ---------------- CSR build: fold copies + hierarchical exclusive scan ----------------------
// Per row: read 8 copy-counts, write back per-copy exclusive bases (in place), scan totals.
__global__ __launch_bounds__(SCAN_B) void scan1_kernel(int* __restrict__ counts,  // [NCOPY][N]
                                                       int* __restrict__ offsets,
                                                       int* __restrict__ partials) {
    __shared__ int wsum[SCAN_B / 64];
    const int tid = threadIdx.x;
    const int gid = blockIdx.x * SCAN_B + tid;
    const int lane = tid & 63, wave = tid >> 6;

    int tot = 0;
    if (gid < N_NODES) {
        int pre[NCOPY];
        #pragma unroll
        for (int k = 0; k < NCOPY; k++) {
            int v = counts[k * N_NODES + gid];
            pre[k] = tot; tot += v;
        }
        #pragma unroll
        for (int k = 0; k < NCOPY; k++) counts[k * N_NODES + gid] = pre[k];
    }

    int x = tot;                               // inclusive wave scan of row totals
    #pragma unroll
    for (int d = 1; d < 64; d <<= 1) {
        int y = __shfl_up(x, d, 64);
        if (lane >= d) x += y;
    }
    if (lane == 63) wsum[wave] = x;
    __syncthreads();
    if (tid == 0) {                            // serial scan of 16 wave sums
        int run = 0;
        #pragma unroll
        for (int w = 0; w < SCAN_B / 64; w++) { int t = wsum[w]; wsum[w] = run; run += t; }
        partials[blockIdx.x] = run;            // block total
    }
    __syncthreads();
    if (gid < N_NODES) offsets[gid] = x - tot + wsum[wave];   // block-local exclusive
}

__global__ __launch_bounds__(128) void scan2_kernel(int* __restrict__ partials) {
    __shared__ int wsum[2];
    const int tid = threadIdx.x, lane = tid & 63, wave = tid >> 6;
    const int c = (tid < SCAN_NB) ? partials[tid] : 0;
    int x = c;
    #pragma unroll
    for (int d = 1; d < 64; d <<= 1) {
        int y = __shfl_up(x, d, 64);
        if (lane >= d) x += y;
    }
    if (lane == 63) wsum[wave] = x;
    __syncthreads();
    const int base = (wave == 1) ? wsum[0] : 0;
    if (tid < SCAN_NB) partials[tid] = x - c + base;        // exclusive
}

__global__ __launch_bounds__(SCAN_B) void scan3_kernel(int* __restrict__ offsets,
                                                       const int* __restrict__ partials) {
    const int gid = blockIdx.x * SCAN_B + threadIdx.x;
    if (gid < N_NODES) offsets[gid] += partials[blockIdx.x];
    if (gid == 0) offsets[N_NODES] = N_EDGES;
}

// ---------------- CSR build: scatter (no atomics; one nt 8B store per edge) -----------------
__global__ __launch_bounds__(256) void scatter_kernel(const int* __restrict__ edge_row,
                                                      const int* __restrict__ edge_col,
                                                      const float* __restrict__ edge_val,
                                                      const int* __restrict__ offsets,
                                                      const int* __restrict__ counts,  // bases
                                                      const ushort* __restrict__ rank,
                                                      iv2* __restrict__ epack) {
    int e = blockIdx.x * 256 + threadIdx.x;
    if (e >= N_EDGES) return;
    const int copy = blockIdx.x & (NCOPY - 1);   // identical grid => same copy as hist
    const int r = edge_row[e];
    const int p = offsets[r] + counts[copy * N_NODES + r] + (int)rank[e];
    iv2 pk;
    pk.x = edge_col[e];
    pk.y = __float_as_int(edge_val[e]);
    __builtin_nontemporal_store(pk, epack + p);
}

// ---------------- Accumulate: 16 lanes/row, 4-wide unroll, fused ReLU -----------------------
__global__ __launch_bounds__(256) void accum_kernel(const ushort* __restrict__ support,
                                                    const int* __restrict__ offsets,
                                                    const iv2* __restrict__ epack,
                                                    float* __restrict__ out) {
    const int tid = threadIdx.x;
    const int row  = (blockIdx.x * 256 + tid) >> 4;       // one 16-lane group per row
    const int part = tid & 15;
    if (row >= N_NODES) return;

    const int start = offsets[row], end = offsets[row + 1];
    float acc0[8], acc1[8];
    #pragma unroll
    for (int i = 0; i < 8; i++) { acc0[i] = 0.f; acc1[i] = 0.f; }

    int e = start;
    if ((e & 1) && e < end) {                 // align to 16B for iv4 loads
        const iv2 pa = epack[e];
        U16B sa; sa.u4 = *(const uint4*)(support + (size_t)pa.x * D + part * 8);
        const float va = __int_as_float(pa.y);
        #pragma unroll
        for (int i = 0; i < 8; i++) acc0[i] += bf16_to_f32(sa.us[i]) * va;
        ++e;
    }
    for (; e + 3 < end; e += 4) {             // 4 gathers in flight
        const iv4 qa = ((const iv4*)(epack + e))[0];      // edges e, e+1
        const iv4 qb = ((const iv4*)(epack + e))[1];      // edges e+2, e+3
        U16B s0; s0.u4 = *(const uint4*)(support + (size_t)qa.x * D + part * 8);
        U16B s1; s1.u4 = *(const uint4*)(support + (size_t)qa.z * D + part * 8);
        U16B s2; s2.u4 = *(const uint4*)(support + (size_t)qb.x * D + part * 8);
        U16B s3; s3.u4 = *(const uint4*)(support + (size_t)qb.z * D + part * 8);
        const float v0 = __int_as_float(qa.y);
        const float v1 = __int_as_float(qa.w);
        const float v2 = __int_as_float(qb.y);
        const float v3 = __int_as_float(qb.w);
        #pragma unroll
        for (int i = 0; i < 8; i++) {
            acc0[i] += bf16_to_f32(s0.us[i]) * v0;
            acc1[i] += bf16_to_f32(s1.us[i]) * v1;
            acc0[i] += bf16_to_f32(s2.us[i]) * v2;
            acc1[i] += bf16_to_f32(s3.us[i]) * v3;
        }
    }
    for (; e < end; ++e) {
        const iv2 pa = epack[e];
        U16B sa; sa.u4 = *(const uint4*)(support + (size_t)pa.x * D + part * 8);
        const float va = __int_as_float(pa.y);
        #pragma unroll
        for (int i = 0; i < 8; i++) acc0[i] += bf16_to_f32(sa.us[i]) * va;
    }

    fv4 lo, hi;
    lo.x = fmaxf(acc0[0] + acc1[0], 0.f); lo.y = fmaxf(acc0[1] + acc1[1], 0.f);
    lo.z = fmaxf(acc0[2] + acc1[2], 0.f); lo.w = fmaxf(acc0[3] + acc1[3], 0.f);
    hi.x = fmaxf(acc0[4] + acc1[4], 0.f); hi.y = fmaxf(acc0[5] + acc1[5], 0.f);
    hi.z = fmaxf(acc0[6] + acc1[6], 0.f); hi.w = fmaxf(acc0[7] + acc1[7], 0.f);
    float* dst = out + (size_t)row * D + part * 8;
    __builtin_nontemporal_store(lo, (fv4*)dst);        // out has zero reuse: don't pollute
    __builtin_nontemporal_store(hi, (fv4*)(dst + 4));  // L2/L3 (support gather lives there)
}

// ================= Fallback path (R3 atomic spmm) if ws too small ===========================
__global__ __launch_bounds__(256) void zero_f4_kernel(float4* __restrict__ acc, int n4) {
    int i = blockIdx.x * 256 + threadIdx.x;
    if (i < n4) acc[i] = make_float4(0.f, 0.f, 0.f, 0.f);
}
__global__ __launch_bounds__(256) void spmm_kernel(const ushort* __restrict__ support,
                                                   const float* __restrict__ edge_val,
                                                   const int* __restrict__ edge_row,
                                                   const int* __restrict__ edge_col,
                                                   float* __restrict__ out) {
    const long gtid = (long)blockIdx.x * 256 + threadIdx.x;
    const int edge = (int)(gtid >> 4);
    const int part = (int)(gtid & 15);
    if (edge >= N_EDGES) return;
    const int col = edge_col[edge];
    const int row = edge_row[edge];
    const float v = edge_val[edge];
    U16B s; s.u4 = *(const uint4*)(support + (size_t)col * D + part * 8);
    float* dst = out + (size_t)row * D + part * 8;
    #pragma unroll
    for (int i = 0; i < 8; i++) unsafeAtomicAdd(dst + i, bf16_to_f32(s.us[i]) * v);
}
__global__ __launch_bounds__(256) void relu_kernel(float4* __restrict__ out, int n4) {
    int i = blockIdx.x * 256 + threadIdx.x;
    if (i >= n4) return;
    float4 a = out[i];
    a.x = fmaxf(a.x, 0.f); a.y = fmaxf(a.y, 0.f);
    a.z = fmaxf(a.z, 0.f); a.w = fmaxf(a.w, 0.f);
    out[i] = a;
}

extern "C" void kernel_launch(void* const* d_in, const int* in_sizes, int n_in,
                              void* d_out, int out_size, void* d_ws, size_t ws_size,
                              hipStream_t stream) {
    (void)in_sizes; (void)n_in; (void)out_size;
    const float* feat     = (const float*)d_in[0];
    const float* W        = (const float*)d_in[1];
    const float* edge_val = (const float*)d_in[2];
    const int*   edge_row = (const int*)d_in[3];
    const int*   edge_col = (const int*)d_in[4];
    float* out = (float*)d_out;

    // ws layout (~45.2 MB)
    char* ws = (char*)d_ws;
    size_t o = 0;
    ushort* support = (ushort*)(ws + o); o += (size_t)N_NODES * D * sizeof(ushort);  // 25.6 MB
    int*    offsets = (int*)(ws + o);    o += ((size_t)(N_NODES + 1) * 4 + 15) & ~15ull;
    int*    counts  = (int*)(ws + o);    o += (size_t)NCOPY * N_NODES * 4;           // 3.2 MB
    int*    partials= (int*)(ws + o);    o += ((size_t)SCAN_NB * 4 + 15) & ~15ull;
    ushort* rank    = (ushort*)(ws + o); o += (size_t)N_EDGES * 2;                   // 3.2 MB
    iv2*    epack   = (iv2*)(ws + o);    o += (size_t)N_EDGES * 8;                   // 12.8 MB
    const size_t needed = o;

    const int eblocks = (N_EDGES + 255) / 256;

    if (ws_size >= needed) {
        // CSR path: fp32-atomic-free; int atomics spread over 8 XCD-affine copies
        zero_int_kernel<<<(NCOPY * N_NODES + 255) / 256, 256, 0, stream>>>(counts,
                                                                           NCOPY * N_NODES);
        gemm_kernel<<<(N_NODES + 63) / 64, 256, 0, stream>>>(feat, W, support);
        hist_kernel<<<eblocks, 256, 0, stream>>>(edge_row, counts, rank);
        scan1_kernel<<<SCAN_NB, SCAN_B, 0, stream>>>(counts, offsets, partials);
        scan2_kernel<<<1, 128, 0, stream>>>(partials);
        scan3_kernel<<<SCAN_NB, SCAN_B, 0, stream>>>(offsets, partials);
        scatter_kernel<<<eblocks, 256, 0, stream>>>(edge_row, edge_col, edge_val,
                                                    offsets, counts, rank, epack);
        accum_kernel<<<(N_NODES * 16 + 255) / 256, 256, 0, stream>>>(support, offsets,
                                                                     epack, out);
    } else {
        // R3 fallback: atomic spmm into d_out
        const int n4 = N_NODES * D / 4;
        zero_f4_kernel<<<(n4 + 255) / 256, 256, 0, stream>>>((float4*)out, n4);
        gemm_kernel<<<(N_NODES + 63) / 64, 256, 0, stream>>>(feat, W, support);
        spmm_kernel<<<(int)(((long)N_EDGES * 16 + 255) / 256), 256, 0, stream>>>(
            support, edge_val, edge_row, edge_col, out);
        relu_kernel<<<(n4 + 255) / 256, 256, 0, stream>>>((float4*)out, n4);
    }
}

// Round 10
// 315.605 us; speedup vs baseline: 18.1116x; 1.0105x over previous
//
#include <hip/hip_runtime.h>
#include <hip/hip_bf16.h>

// GraphConv: out = relu( scatter_add_{edges}( edge_val * (feat @ W)[edge_col] -> edge_row ) )
// Dtypes: feat/W/edge_val = float32, edge_row/col = int32, OUTPUT = float32.
//
// R9 post-mortem: accum ILP was a null result (70us, memory-system bound, near floor);
// hist's 8-copy fix worked (out of top-5). ~250us of 319 is tail spread over 7 launches.
// R10: (a) grid-fuse gemm+hist (independent; MFMA-bound + atomic-latency-bound overlap),
//      (b) single-pass decoupled-lookback scan (replaces scan1/2/3),
//      (c) 5 launches total. fp8 support REJECTED on error arithmetic (would absmax ~5 > 3.32).

#define N_NODES 100000
#define N_EDGES 1600000
#define D 128
#define NCOPY 8
#define SCAN_B 1024
#define SCAN_NB ((N_NODES + SCAN_B - 1) / SCAN_B)   // 98
#define GEMM_BLOCKS ((N_NODES + 63) / 64)           // 1563
#define EDGE_BLOCKS ((N_EDGES + 255) / 256)         // 6250

typedef __attribute__((ext_vector_type(8))) short short8;
typedef __attribute__((ext_vector_type(4))) float floatx4;
typedef int  iv2 __attribute__((ext_vector_type(2)));   // nt-store-compatible int2
typedef int  iv4 __attribute__((ext_vector_type(4)));
typedef float fv4 __attribute__((ext_vector_type(4)));  // nt-store-compatible float4

union U16B { uint4 u4; short8 s8; uint u[4]; ushort us[8]; };

__device__ __forceinline__ ushort f32_to_bf16(float f) {
    uint b = __float_as_uint(f);
    return (ushort)((b + 0x7FFFu + ((b >> 16) & 1u)) >> 16);   // RNE; inputs finite
}
__device__ __forceinline__ float bf16_to_f32(ushort u) {
    return __uint_as_float((uint)u << 16);
}

// ---------------- zero counts (8 copies) + lookback state -----------------------------------
__global__ __launch_bounds__(256) void zero_int_kernel(int* __restrict__ p, int n) {
    int i = blockIdx.x * 256 + threadIdx.x;
    if (i < n) p[i] = 0;
}

// ---------------- GEMM body: support = bf16( fp32 feat @ fp32 W ) via MFMA ------------------
__device__ __forceinline__ void gemm_body(const float* __restrict__ feat,
                                          const float* __restrict__ W,
                                          ushort* __restrict__ support,
                                          ushort* __restrict__ Bp, int bid) {
    const int tid = threadIdx.x;
    for (int e = tid; e < D * D; e += 256) {
        int k = e >> 7, n = e & 127;
        Bp[(((k >> 3) * D + n) << 3) | (k & 7)] = f32_to_bf16(W[e]);
    }
    __syncthreads();

    const int wave = tid >> 6, lane = tid & 63;
    const int row0 = bid * 64 + wave * 16;
    if (row0 >= N_NODES) return;              // wave-uniform, after barrier

    const int m = lane & 15, g = lane >> 4;
    floatx4 acc[8];
    const floatx4 z = {0.f, 0.f, 0.f, 0.f};
    #pragma unroll
    for (int t = 0; t < 8; t++) acc[t] = z;

    const float* arow = feat + (size_t)(row0 + m) * D;
    #pragma unroll
    for (int s = 0; s < 4; s++) {             // k-steps of 32
        float4 a0 = *(const float4*)(arow + s * 32 + g * 8);
        float4 a1 = *(const float4*)(arow + s * 32 + g * 8 + 4);
        U16B a;
        a.us[0] = f32_to_bf16(a0.x); a.us[1] = f32_to_bf16(a0.y);
        a.us[2] = f32_to_bf16(a0.z); a.us[3] = f32_to_bf16(a0.w);
        a.us[4] = f32_to_bf16(a1.x); a.us[5] = f32_to_bf16(a1.y);
        a.us[6] = f32_to_bf16(a1.z); a.us[7] = f32_to_bf16(a1.w);
        #pragma unroll
        for (int t = 0; t < 8; t++) {         // 8 col-tiles of 16
            const int chunk = (s * 4 + g) * D + t * 16 + m;
            U16B b; b.u4 = *(const uint4*)(Bp + chunk * 8);
            acc[t] = __builtin_amdgcn_mfma_f32_16x16x32_bf16(a.s8, b.s8, acc[t], 0, 0, 0);
        }
    }
    // C/D: col = lane&15, row = (lane>>4)*4 + reg  (m89-verified)
    #pragma unroll
    for (int t = 0; t < 8; t++) {
        #pragma unroll
        for (int r = 0; r < 4; r++) {
            const int row = row0 + g * 4 + r;
            const int col = t * 16 + m;
            support[(size_t)row * D + col] = f32_to_bf16(acc[t][r]);
        }
    }
}

// ---------------- hist body: 8 XCD-affine count copies + per-edge rank ----------------------
__device__ __forceinline__ void hist_body(const int* __restrict__ edge_row,
                                          int* __restrict__ counts,   // [NCOPY][N]
                                          ushort* __restrict__ rank, int hb) {
    int e = hb * 256 + threadIdx.x;
    if (e >= N_EDGES) return;
    const int copy = hb & (NCOPY - 1);        // scatter recomputes identical mapping
    rank[e] = (ushort)atomicAdd(&counts[copy * N_NODES + edge_row[e]], 1);
}

// ---------------- fused gemm || hist (independent stages share one dispatch) ----------------
__global__ __launch_bounds__(256) void gemm_hist_kernel(const float* __restrict__ feat,
                                                        const float* __restrict__ W,
                                                        ushort* __restrict__ support,
                                                        const int* __restrict__ edge_row,
                                                        int* __restrict__ counts,
                                                        ushort* __restrict__ rank) {
    __shared__ ushort Bp[D * D];   // 32 KB (hist blocks don't touch it)
    if ((int)blockIdx.x < GEMM_BLOCKS)
        gemm_body(feat, W, support, Bp, blockIdx.x);
    else
        hist_body(edge_row, counts, rank, blockIdx.x - GEMM_BLOCKS);
}

// ---------------- single-pass scan: fold 8 copies + decoupled lookback ----------------------
// st[b] = (state<<30)|value; state 1 = aggregate published, 2 = inclusive prefix published.
// 98 blocks x 1024 thr are co-resident on 256 CUs -> lookback cannot deadlock.
__global__ __launch_bounds__(SCAN_B) void scan_kernel(int* __restrict__ counts,  // -> bases
                                                      int* __restrict__ offsets,
                                                      uint* __restrict__ st) {
    __shared__ int wsum[SCAN_B / 64];
    __shared__ int s_base;
    const int tid = threadIdx.x, b = blockIdx.x;
    const int gid = b * SCAN_B + tid;
    const int lane = tid & 63, wave = tid >> 6;

    int tot = 0;
    if (gid < N_NODES) {
        int pre[NCOPY];
        #pragma unroll
        for (int k = 0; k < NCOPY; k++) {
            int v = counts[k * N_NODES + gid];
            pre[k] = tot; tot += v;
        }
        #pragma unroll
        for (int k = 0; k < NCOPY; k++) counts[k * N_NODES + gid] = pre[k];  // per-copy bases
    }

    int x = tot;                               // inclusive wave scan of row totals
    #pragma unroll
    for (int d = 1; d < 64; d <<= 1) {
        int y = __shfl_up(x, d, 64);
        if (lane >= d) x += y;
    }
    if (lane == 63) wsum[wave] = x;
    __syncthreads();
    if (tid == 0) {
        int run = 0;
        #pragma unroll
        for (int w = 0; w < SCAN_B / 64; w++) { int t = wsum[w]; wsum[w] = run; run += t; }
        // publish aggregate, then look back for exclusive prefix
        __hip_atomic_store(&st[b], (1u << 30) | (uint)run,
                           __ATOMIC_RELEASE, __HIP_MEMORY_SCOPE_AGENT);
        int P = 0;
        for (int j = b - 1; j >= 0; ) {
            uint w;
            do {
                w = __hip_atomic_load(&st[j], __ATOMIC_ACQUIRE, __HIP_MEMORY_SCOPE_AGENT);
            } while ((w >> 30) == 0u);
            P += (int)(w & 0x3FFFFFFFu);
            if ((w >> 30) == 2u) break;
            --j;
        }
        __hip_atomic_store(&st[b], (2u << 30) | (uint)(P + run),
                           __ATOMIC_RELEASE, __HIP_MEMORY_SCOPE_AGENT);
        s_base = P;
    }
    __syncthreads();
    if (gid < N_NODES) offsets[gid] = s_base + wsum[wave] + (x - tot);
    if (gid == 0) offsets[N_NODES] = N_EDGES;
}

// ---------------- scatter (no atomics; one nt 8B store per edge) ----------------------------
__global__ __launch_bounds__(256) void scatter_kernel(const int* __restrict__ edge_row,
                                                      const int* __restrict__ edge_col,
                                                      const float* __restrict__ edge_val,
                                                      const int* __restrict__ offsets,
                                                      const int* __restrict__ counts,  // bases
                                                      const ushort* __restrict__ rank,
                                                      iv2* __restrict__ epack) {
    int e = blockIdx.x * 256 + threadIdx.x;
    if (e >= N_EDGES) return;
    const int copy = blockIdx.x & (NCOPY - 1);   // matches hist's hb & 7
    const int r = edge_row[e];
    const int p = offsets[r] + counts[copy * N_NODES + r] + (int)rank[e];
    iv2 pk;
    pk.x = edge_col[e];
    pk.y = __float_as_int(edge_val[e]);
    __builtin_nontemporal_store(pk, epack + p);
}

// ---------------- Accumulate: 16 lanes/row, 4-wide unroll, fused ReLU -----------------------
__global__ __launch_bounds__(256) void accum_kernel(const ushort* __restrict__ support,
                                                    const int* __restrict__ offsets,
                                                    const iv2* __restrict__ epack,
                                                    float* __restrict__ out) {
    const int tid = threadIdx.x;
    const int row  = (blockIdx.x * 256 + tid) >> 4;       // one 16-lane group per row
    const int part = tid & 15;
    if (row >= N_NODES) return;

    const int start = offsets[row], end = offsets[row + 1];
    float acc0[8], acc1[8];
    #pragma unroll
    for (int i = 0; i < 8; i++) { acc0[i] = 0.f; acc1[i] = 0.f; }

    int e = start;
    if ((e & 1) && e < end) {                 // align to 16B for iv4 loads
        const iv2 pa = epack[e];
        U16B sa; sa.u4 = *(const uint4*)(support + (size_t)pa.x * D + part * 8);
        const float va = __int_as_float(pa.y);
        #pragma unroll
        for (int i = 0; i < 8; i++) acc0[i] += bf16_to_f32(sa.us[i]) * va;
        ++e;
    }
    for (; e + 3 < end; e += 4) {             // 4 gathers in flight
        const iv4 qa = ((const iv4*)(epack + e))[0];      // edges e, e+1
        const iv4 qb = ((const iv4*)(epack + e))[1];      // edges e+2, e+3
        U16B s0; s0.u4 = *(const uint4*)(support + (size_t)qa.x * D + part * 8);
        U16B s1; s1.u4 = *(const uint4*)(support + (size_t)qa.z * D + part * 8);
        U16B s2; s2.u4 = *(const uint4*)(support + (size_t)qb.x * D + part * 8);
        U16B s3; s3.u4 = *(const uint4*)(support + (size_t)qb.z * D + part * 8);
        const float v0 = __int_as_float(qa.y);
        const float v1 = __int_as_float(qa.w);
        const float v2 = __int_as_float(qb.y);
        const float v3 = __int_as_float(qb.w);
        #pragma unroll
        for (int i = 0; i < 8; i++) {
            acc0[i] += bf16_to_f32(s0.us[i]) * v0;
            acc1[i] += bf16_to_f32(s1.us[i]) * v1;
            acc0[i] += bf16_to_f32(s2.us[i]) * v2;
            acc1[i] += bf16_to_f32(s3.us[i]) * v3;
        }
    }
    for (; e < end; ++e) {
        const iv2 pa = epack[e];
        U16B sa; sa.u4 = *(const uint4*)(support + (size_t)pa.x * D + part * 8);
        const float va = __int_as_float(pa.y);
        #pragma unroll
        for (int i = 0; i < 8; i++) acc0[i] += bf16_to_f32(sa.us[i]) * va;
    }

    fv4 lo, hi;
    lo.x = fmaxf(acc0[0] + acc1[0], 0.f); lo.y = fmaxf(acc0[1] + acc1[1], 0.f);
    lo.z = fmaxf(acc0[2] + acc1[2], 0.f); lo.w = fmaxf(acc0[3] + acc1[3], 0.f);
    hi.x = fmaxf(acc0[4] + acc1[4], 0.f); hi.y = fmaxf(acc0[5] + acc1[5], 0.f);
    hi.z = fmaxf(acc0[6] + acc1[6], 0.f); hi.w = fmaxf(acc0[7] + acc1[7], 0.f);
    float* dst = out + (size_t)row * D + part * 8;
    __builtin_nontemporal_store(lo, (fv4*)dst);        // out has zero reuse: don't pollute
    __builtin_nontemporal_store(hi, (fv4*)(dst + 4));  // L2/L3 (support gather lives there)
}

// ================= Fallback path (R3 atomic spmm) if ws too small ===========================
__global__ __launch_bounds__(256) void gemm_kernel(const float* __restrict__ feat,
                                                   const float* __restrict__ W,
                                                   ushort* __restrict__ support) {
    __shared__ ushort Bp[D * D];
    gemm_body(feat, W, support, Bp, blockIdx.x);
}
__global__ __launch_bounds__(256) void zero_f4_kernel(float4* __restrict__ acc, int n4) {
    int i = blockIdx.x * 256 + threadIdx.x;
    if (i < n4) acc[i] = make_float4(0.f, 0.f, 0.f, 0.f);
}
__global__ __launch_bounds__(256) void spmm_kernel(const ushort* __restrict__ support,
                                                   const float* __restrict__ edge_val,
                                                   const int* __restrict__ edge_row,
                                                   const int* __restrict__ edge_col,
                                                   float* __restrict__ out) {
    const long gtid = (long)blockIdx.x * 256 + threadIdx.x;
    const int edge = (int)(gtid >> 4);
    const int part = (int)(gtid & 15);
    if (edge >= N_EDGES) return;
    const int col = edge_col[edge];
    const int row = edge_row[edge];
    const float v = edge_val[edge];
    U16B s; s.u4 = *(const uint4*)(support + (size_t)col * D + part * 8);
    float* dst = out + (size_t)row * D + part * 8;
    #pragma unroll
    for (int i = 0; i < 8; i++) unsafeAtomicAdd(dst + i, bf16_to_f32(s.us[i]) * v);
}
__global__ __launch_bounds__(256) void relu_kernel(float4* __restrict__ out, int n4) {
    int i = blockIdx.x * 256 + threadIdx.x;
    if (i >= n4) return;
    float4 a = out[i];
    a.x = fmaxf(a.x, 0.f); a.y = fmaxf(a.y, 0.f);
    a.z = fmaxf(a.z, 0.f); a.w = fmaxf(a.w, 0.f);
    out[i] = a;
}

extern "C" void kernel_launch(void* const* d_in, const int* in_sizes, int n_in,
                              void* d_out, int out_size, void* d_ws, size_t ws_size,
                              hipStream_t stream) {
    (void)in_sizes; (void)n_in; (void)out_size;
    const float* feat     = (const float*)d_in[0];
    const float* W        = (const float*)d_in[1];
    const float* edge_val = (const float*)d_in[2];
    const int*   edge_row = (const int*)d_in[3];
    const int*   edge_col = (const int*)d_in[4];
    float* out = (float*)d_out;

    // ws layout (~45.2 MB; counts and st contiguous so one zero pass covers both)
    char* ws = (char*)d_ws;
    size_t o = 0;
    ushort* support = (ushort*)(ws + o); o += (size_t)N_NODES * D * sizeof(ushort);  // 25.6 MB
    int*    offsets = (int*)(ws + o);    o += ((size_t)(N_NODES + 1) * 4 + 15) & ~15ull;
    int*    counts  = (int*)(ws + o);    o += (size_t)NCOPY * N_NODES * 4;           // 3.2 MB
    uint*   st      = (uint*)(ws + o);   o += 128 * 4;                               // lookback
    ushort* rank    = (ushort*)(ws + o); o += (size_t)N_EDGES * 2;                   // 3.2 MB
    iv2*    epack   = (iv2*)(ws + o);    o += (size_t)N_EDGES * 8;                   // 12.8 MB
    const size_t needed = o;

    if (ws_size >= needed) {
        const int nz = NCOPY * N_NODES + 128;   // counts + st in one pass
        zero_int_kernel<<<(nz + 255) / 256, 256, 0, stream>>>(counts, nz);
        gemm_hist_kernel<<<GEMM_BLOCKS + EDGE_BLOCKS, 256, 0, stream>>>(
            feat, W, support, edge_row, counts, rank);
        scan_kernel<<<SCAN_NB, SCAN_B, 0, stream>>>(counts, offsets, st);
        scatter_kernel<<<EDGE_BLOCKS, 256, 0, stream>>>(edge_row, edge_col, edge_val,
                                                        offsets, counts, rank, epack);
        accum_kernel<<<(N_NODES * 16 + 255) / 256, 256, 0, stream>>>(support, offsets,
                                                                     epack, out);
    } else {
        // R3 fallback: atomic spmm into d_out
        const int n4 = N_NODES * D / 4;
        zero_f4_kernel<<<(n4 + 255) / 256, 256, 0, stream>>>((float4*)out, n4);
        gemm_kernel<<<GEMM_BLOCKS, 256, 0, stream>>>(feat, W, support);
        spmm_kernel<<<(int)(((long)N_EDGES * 16 + 255) / 256), 256, 0, stream>>>(
            support, edge_val, edge_row, edge_col, out);
        relu_kernel<<<(n4 + 255) / 256, 256, 0, stream>>>((float4*)out, n4);
    }
}

// Round 11
// 301.165 us; speedup vs baseline: 18.9800x; 1.0479x over previous
//
#include <hip/hip_runtime.h>
#include <hip/hip_bf16.h>

// GraphConv: out = relu( scatter_add_{edges}( edge_val * (feat @ W)[edge_col] -> edge_row ) )
// Dtypes: feat/W/edge_val = float32, edge_row/col = int32, OUTPUT = float32.
//
// R10 post-mortem: gemm_hist 83.5us @ 37.8% occupancy (32KB LDS allocated for hist blocks
// too -> 5 blocks/CU; hist is atomic-latency-bound and needs waves). Scan lookback was
// serial in tid0 (~97 dependent loads).
// R11: (a) Bp 32KB -> 16KB (two k-halves) => 8-10 blocks/CU; interleaved gemm/hist block
//      mapping (every 5th block is gemm). (b) 64-lane parallel lookback in scan.

#define N_NODES 100000
#define N_EDGES 1600000
#define D 128
#define NCOPY 8
#define SCAN_B 1024
#define SCAN_NB ((N_NODES + SCAN_B - 1) / SCAN_B)   // 98
#define GEMM_BLOCKS ((N_NODES + 63) / 64)           // 1563
#define EDGE_BLOCKS ((N_EDGES + 255) / 256)         // 6250

typedef __attribute__((ext_vector_type(8))) short short8;
typedef __attribute__((ext_vector_type(4))) float floatx4;
typedef int  iv2 __attribute__((ext_vector_type(2)));   // nt-store-compatible int2
typedef int  iv4 __attribute__((ext_vector_type(4)));
typedef float fv4 __attribute__((ext_vector_type(4)));  // nt-store-compatible float4

union U16B { uint4 u4; short8 s8; uint u[4]; ushort us[8]; };

__device__ __forceinline__ ushort f32_to_bf16(float f) {
    uint b = __float_as_uint(f);
    return (ushort)((b + 0x7FFFu + ((b >> 16) & 1u)) >> 16);   // RNE; inputs finite
}
__device__ __forceinline__ float bf16_to_f32(ushort u) {
    return __uint_as_float((uint)u << 16);
}

// ---------------- zero counts (8 copies) + lookback state -----------------------------------
__global__ __launch_bounds__(256) void zero_int_kernel(int* __restrict__ p, int n) {
    int i = blockIdx.x * 256 + threadIdx.x;
    if (i < n) p[i] = 0;
}

// ---------------- GEMM body: support = bf16( fp32 feat @ fp32 W ), 16KB LDS ----------------
// W staged in two k-halves (k in [h*64, h*64+64)); fragment layout per half identical to the
// 32KB version with kk = k - h*64. All waves execute barriers (inactive waves guarded).
__device__ __forceinline__ void gemm_body(const float* __restrict__ feat,
                                          const float* __restrict__ W,
                                          ushort* __restrict__ support,
                                          ushort* __restrict__ Bp /*64*D*/, int bid) {
    const int tid = threadIdx.x;
    const int wave = tid >> 6, lane = tid & 63;
    const int row0 = bid * 64 + wave * 16;
    const bool active = (row0 < N_NODES);     // wave-uniform
    const int m = lane & 15, g = lane >> 4;

    floatx4 acc[8];
    const floatx4 z = {0.f, 0.f, 0.f, 0.f};
    #pragma unroll
    for (int t = 0; t < 8; t++) acc[t] = z;

    const float* arow = feat + (size_t)(row0 + m) * D;
    #pragma unroll
    for (int h = 0; h < 2; h++) {             // two k-halves of 64
        if (h) __syncthreads();               // prev readers done before overwrite
        for (int e = tid; e < 64 * D; e += 256) {
            int kk = e >> 7, n = e & 127;
            Bp[(((kk >> 3) * D + n) << 3) | (kk & 7)] = f32_to_bf16(W[(h * 64 + kk) * D + n]);
        }
        __syncthreads();
        if (active) {
            #pragma unroll
            for (int ss = 0; ss < 2; ss++) {  // k-steps of 32 within half
                const int s = h * 2 + ss;
                float4 a0 = *(const float4*)(arow + s * 32 + g * 8);
                float4 a1 = *(const float4*)(arow + s * 32 + g * 8 + 4);
                U16B a;
                a.us[0] = f32_to_bf16(a0.x); a.us[1] = f32_to_bf16(a0.y);
                a.us[2] = f32_to_bf16(a0.z); a.us[3] = f32_to_bf16(a0.w);
                a.us[4] = f32_to_bf16(a1.x); a.us[5] = f32_to_bf16(a1.y);
                a.us[6] = f32_to_bf16(a1.z); a.us[7] = f32_to_bf16(a1.w);
                #pragma unroll
                for (int t = 0; t < 8; t++) { // 8 col-tiles of 16
                    const int chunk = (ss * 4 + g) * D + t * 16 + m;
                    U16B b; b.u4 = *(const uint4*)(Bp + chunk * 8);
                    acc[t] = __builtin_amdgcn_mfma_f32_16x16x32_bf16(a.s8, b.s8, acc[t], 0, 0, 0);
                }
            }
        }
    }
    if (active) {
        // C/D: col = lane&15, row = (lane>>4)*4 + reg  (m89-verified)
        #pragma unroll
        for (int t = 0; t < 8; t++) {
            #pragma unroll
            for (int r = 0; r < 4; r++) {
                const int row = row0 + g * 4 + r;
                const int col = t * 16 + m;
                support[(size_t)row * D + col] = f32_to_bf16(acc[t][r]);
            }
        }
    }
}

// ---------------- hist body: 8 XCD-affine count copies + per-edge rank ----------------------
__device__ __forceinline__ void hist_body(const int* __restrict__ edge_row,
                                          int* __restrict__ counts,   // [NCOPY][N]
                                          ushort* __restrict__ rank, int hb) {
    int e = hb * 256 + threadIdx.x;
    if (e >= N_EDGES) return;
    const int copy = hb & (NCOPY - 1);        // scatter recomputes identical mapping
    rank[e] = (ushort)atomicAdd(&counts[copy * N_NODES + edge_row[e]], 1);
}

// ---------------- fused gemm || hist, interleaved (every 5th block is gemm) -----------------
__global__ __launch_bounds__(256) void gemm_hist_kernel(const float* __restrict__ feat,
                                                        const float* __restrict__ W,
                                                        ushort* __restrict__ support,
                                                        const int* __restrict__ edge_row,
                                                        int* __restrict__ counts,
                                                        ushort* __restrict__ rank) {
    __shared__ ushort Bp[64 * D];   // 16 KB
    const int b = blockIdx.x;
    const int q = b / 5, r = b - q * 5;       // 7813 blocks: b%5==0 -> gemm (1563), else hist
    if (r == 0)
        gemm_body(feat, W, support, Bp, q);
    else
        hist_body(edge_row, counts, rank, b - q - 1);   // hist_id 0..6249, bijective
}

// ---------------- single-pass scan: fold 8 copies + PARALLEL decoupled lookback -------------
// st[b] = (state<<30)|value; 1 = aggregate published, 2 = inclusive prefix published.
// 98 blocks co-resident on 256 CUs; wave 0 inspects 64 predecessors per window.
__global__ __launch_bounds__(SCAN_B) void scan_kernel(int* __restrict__ counts,  // -> bases
                                                      int* __restrict__ offsets,
                                                      uint* __restrict__ st) {
    __shared__ int wsum[SCAN_B / 64];
    __shared__ int s_run, s_base;
    const int tid = threadIdx.x, b = blockIdx.x;
    const int gid = b * SCAN_B + tid;
    const int lane = tid & 63, wave = tid >> 6;

    int tot = 0;
    if (gid < N_NODES) {
        int pre[NCOPY];
        #pragma unroll
        for (int k = 0; k < NCOPY; k++) {
            int v = counts[k * N_NODES + gid];
            pre[k] = tot; tot += v;
        }
        #pragma unroll
        for (int k = 0; k < NCOPY; k++) counts[k * N_NODES + gid] = pre[k];  // per-copy bases
    }

    int x = tot;                               // inclusive wave scan of row totals
    #pragma unroll
    for (int d = 1; d < 64; d <<= 1) {
        int y = __shfl_up(x, d, 64);
        if (lane >= d) x += y;
    }
    if (lane == 63) wsum[wave] = x;
    __syncthreads();
    if (tid == 0) {
        int run = 0;
        #pragma unroll
        for (int w = 0; w < SCAN_B / 64; w++) { int t = wsum[w]; wsum[w] = run; run += t; }
        s_run = run;
        __hip_atomic_store(&st[b], (1u << 30) | (uint)run,
                           __ATOMIC_RELEASE, __HIP_MEMORY_SCOPE_AGENT);
    }
    __syncthreads();
    if (wave == 0) {
        int P = 0;
        int base = b;
        bool done = (b == 0);
        while (!done) {
            const int j = base - 1 - lane;     // lane l inspects predecessor b-1-l, ...
            uint w;
            if (j >= 0) {
                do {
                    w = __hip_atomic_load(&st[j], __ATOMIC_ACQUIRE, __HIP_MEMORY_SCOPE_AGENT);
                } while ((w >> 30) == 0u);
            } else w = 2u << 30;               // virtual prefix 0 before block 0
            const unsigned long long m2 = __ballot((w >> 30) == 2u);
            int contrib;
            if (m2) {
                const int fl = (int)__ffsll(m2) - 1;   // nearest published prefix
                contrib = (lane <= fl) ? (int)(w & 0x3FFFFFFFu) : 0;
                done = true;
            } else {
                contrib = (int)(w & 0x3FFFFFFFu);      // 64 aggregates, keep walking
                base -= 64;
            }
            #pragma unroll
            for (int mm = 1; mm < 64; mm <<= 1) contrib += __shfl_xor(contrib, mm, 64);
            P += contrib;
        }
        if (lane == 0) {
            __hip_atomic_store(&st[b], (2u << 30) | (uint)(P + s_run),
                               __ATOMIC_RELEASE, __HIP_MEMORY_SCOPE_AGENT);
            s_base = P;
        }
    }
    __syncthreads();
    if (gid < N_NODES) offsets[gid] = s_base + wsum[wave] + (x - tot);
    if (gid == 0) offsets[N_NODES] = N_EDGES;
}

// ---------------- scatter (no atomics; one nt 8B store per edge) ----------------------------
__global__ __launch_bounds__(256) void scatter_kernel(const int* __restrict__ edge_row,
                                                      const int* __restrict__ edge_col,
                                                      const float* __restrict__ edge_val,
                                                      const int* __restrict__ offsets,
                                                      const int* __restrict__ counts,  // bases
                                                      const ushort* __restrict__ rank,
                                                      iv2* __restrict__ epack) {
    int e = blockIdx.x * 256 + threadIdx.x;
    if (e >= N_EDGES) return;
    const int copy = blockIdx.x & (NCOPY - 1);   // matches hist_id & 7 (same 256-edge chunk)
    const int r = edge_row[e];
    const int p = offsets[r] + counts[copy * N_NODES + r] + (int)rank[e];
    iv2 pk;
    pk.x = edge_col[e];
    pk.y = __float_as_int(edge_val[e]);
    __builtin_nontemporal_store(pk, epack + p);
}

// ---------------- Accumulate: 16 lanes/row, 4-wide unroll, fused ReLU -----------------------
__global__ __launch_bounds__(256) void accum_kernel(const ushort* __restrict__ support,
                                                    const int* __restrict__ offsets,
                                                    const iv2* __restrict__ epack,
                                                    float* __restrict__ out) {
    const int tid = threadIdx.x;
    const int row  = (blockIdx.x * 256 + tid) >> 4;       // one 16-lane group per row
    const int part = tid & 15;
    if (row >= N_NODES) return;

    const int start = offsets[row], end = offsets[row + 1];
    float acc0[8], acc1[8];
    #pragma unroll
    for (int i = 0; i < 8; i++) { acc0[i] = 0.f; acc1[i] = 0.f; }

    int e = start;
    if ((e & 1) && e < end) {                 // align to 16B for iv4 loads
        const iv2 pa = epack[e];
        U16B sa; sa.u4 = *(const uint4*)(support + (size_t)pa.x * D + part * 8);
        const float va = __int_as_float(pa.y);
        #pragma unroll
        for (int i = 0; i < 8; i++) acc0[i] += bf16_to_f32(sa.us[i]) * va;
        ++e;
    }
    for (; e + 3 < end; e += 4) {             // 4 gathers in flight
        const iv4 qa = ((const iv4*)(epack + e))[0];      // edges e, e+1
        const iv4 qb = ((const iv4*)(epack + e))[1];      // edges e+2, e+3
        U16B s0; s0.u4 = *(const uint4*)(support + (size_t)qa.x * D + part * 8);
        U16B s1; s1.u4 = *(const uint4*)(support + (size_t)qa.z * D + part * 8);
        U16B s2; s2.u4 = *(const uint4*)(support + (size_t)qb.x * D + part * 8);
        U16B s3; s3.u4 = *(const uint4*)(support + (size_t)qb.z * D + part * 8);
        const float v0 = __int_as_float(qa.y);
        const float v1 = __int_as_float(qa.w);
        const float v2 = __int_as_float(qb.y);
        const float v3 = __int_as_float(qb.w);
        #pragma unroll
        for (int i = 0; i < 8; i++) {
            acc0[i] += bf16_to_f32(s0.us[i]) * v0;
            acc1[i] += bf16_to_f32(s1.us[i]) * v1;
            acc0[i] += bf16_to_f32(s2.us[i]) * v2;
            acc1[i] += bf16_to_f32(s3.us[i]) * v3;
        }
    }
    for (; e < end; ++e) {
        const iv2 pa = epack[e];
        U16B sa; sa.u4 = *(const uint4*)(support + (size_t)pa.x * D + part * 8);
        const float va = __int_as_float(pa.y);
        #pragma unroll
        for (int i = 0; i < 8; i++) acc0[i] += bf16_to_f32(sa.us[i]) * va;
    }

    fv4 lo, hi;
    lo.x = fmaxf(acc0[0] + acc1[0], 0.f); lo.y = fmaxf(acc0[1] + acc1[1], 0.f);
    lo.z = fmaxf(acc0[2] + acc1[2], 0.f); lo.w = fmaxf(acc0[3] + acc1[3], 0.f);
    hi.x = fmaxf(acc0[4] + acc1[4], 0.f); hi.y = fmaxf(acc0[5] + acc1[5], 0.f);
    hi.z = fmaxf(acc0[6] + acc1[6], 0.f); hi.w = fmaxf(acc0[7] + acc1[7], 0.f);
    float* dst = out + (size_t)row * D + part * 8;
    __builtin_nontemporal_store(lo, (fv4*)dst);        // out has zero reuse: don't pollute
    __builtin_nontemporal_store(hi, (fv4*)(dst + 4));  // L2/L3 (support gather lives there)
}

// ================= Fallback path (R3 atomic spmm) if ws too small ===========================
__global__ __launch_bounds__(256) void gemm_kernel(const float* __restrict__ feat,
                                                   const float* __restrict__ W,
                                                   ushort* __restrict__ support) {
    __shared__ ushort Bp[64 * D];
    gemm_body(feat, W, support, Bp, blockIdx.x);
}
__global__ __launch_bounds__(256) void zero_f4_kernel(float4* __restrict__ acc, int n4) {
    int i = blockIdx.x * 256 + threadIdx.x;
    if (i < n4) acc[i] = make_float4(0.f, 0.f, 0.f, 0.f);
}
__global__ __launch_bounds__(256) void spmm_kernel(const ushort* __restrict__ support,
                                                   const float* __restrict__ edge_val,
                                                   const int* __restrict__ edge_row,
                                                   const int* __restrict__ edge_col,
                                                   float* __restrict__ out) {
    const long gtid = (long)blockIdx.x * 256 + threadIdx.x;
    const int edge = (int)(gtid >> 4);
    const int part = (int)(gtid & 15);
    if (edge >= N_EDGES) return;
    const int col = edge_col[edge];
    const int row = edge_row[edge];
    const float v = edge_val[edge];
    U16B s; s.u4 = *(const uint4*)(support + (size_t)col * D + part * 8);
    float* dst = out + (size_t)row * D + part * 8;
    #pragma unroll
    for (int i = 0; i < 8; i++) unsafeAtomicAdd(dst + i, bf16_to_f32(s.us[i]) * v);
}
__global__ __launch_bounds__(256) void relu_kernel(float4* __restrict__ out, int n4) {
    int i = blockIdx.x * 256 + threadIdx.x;
    if (i >= n4) return;
    float4 a = out[i];
    a.x = fmaxf(a.x, 0.f); a.y = fmaxf(a.y, 0.f);
    a.z = fmaxf(a.z, 0.f); a.w = fmaxf(a.w, 0.f);
    out[i] = a;
}

extern "C" void kernel_launch(void* const* d_in, const int* in_sizes, int n_in,
                              void* d_out, int out_size, void* d_ws, size_t ws_size,
                              hipStream_t stream) {
    (void)in_sizes; (void)n_in; (void)out_size;
    const float* feat     = (const float*)d_in[0];
    const float* W        = (const float*)d_in[1];
    const float* edge_val = (const float*)d_in[2];
    const int*   edge_row = (const int*)d_in[3];
    const int*   edge_col = (const int*)d_in[4];
    float* out = (float*)d_out;

    // ws layout (~45.2 MB; counts and st contiguous so one zero pass covers both)
    char* ws = (char*)d_ws;
    size_t o = 0;
    ushort* support = (ushort*)(ws + o); o += (size_t)N_NODES * D * sizeof(ushort);  // 25.6 MB
    int*    offsets = (int*)(ws + o);    o += ((size_t)(N_NODES + 1) * 4 + 15) & ~15ull;
    int*    counts  = (int*)(ws + o);    o += (size_t)NCOPY * N_NODES * 4;           // 3.2 MB
    uint*   st      = (uint*)(ws + o);   o += 128 * 4;                               // lookback
    ushort* rank    = (ushort*)(ws + o); o += (size_t)N_EDGES * 2;                   // 3.2 MB
    iv2*    epack   = (iv2*)(ws + o);    o += (size_t)N_EDGES * 8;                   // 12.8 MB
    const size_t needed = o;

    if (ws_size >= needed) {
        const int nz = NCOPY * N_NODES + 128;   // counts + st in one pass
        zero_int_kernel<<<(nz + 255) / 256, 256, 0, stream>>>(counts, nz);
        gemm_hist_kernel<<<GEMM_BLOCKS + EDGE_BLOCKS, 256, 0, stream>>>(
            feat, W, support, edge_row, counts, rank);
        scan_kernel<<<SCAN_NB, SCAN_B, 0, stream>>>(counts, offsets, st);
        scatter_kernel<<<EDGE_BLOCKS, 256, 0, stream>>>(edge_row, edge_col, edge_val,
                                                        offsets, counts, rank, epack);
        accum_kernel<<<(N_NODES * 16 + 255) / 256, 256, 0, stream>>>(support, offsets,
                                                                     epack, out);
    } else {
        // R3 fallback: atomic spmm into d_out
        const int n4 = N_NODES * D / 4;
        zero_f4_kernel<<<(n4 + 255) / 256, 256, 0, stream>>>((float4*)out, n4);
        gemm_kernel<<<GEMM_BLOCKS, 256, 0, stream>>>(feat, W, support);
        spmm_kernel<<<(int)(((long)N_EDGES * 16 + 255) / 256), 256, 0, stream>>>(
            support, edge_val, edge_row, edge_col, out);
        relu_kernel<<<(n4 + 255) / 256, 256, 0, stream>>>((float4*)out, n4);
    }
}